// Round 2
// baseline (672.939 us; speedup 1.0000x reference)
//
#include <hip/hip_runtime.h>
#include <math.h>

#define NB 32
#define NL 512
#define NC 64
#define NG 3
#define NT 10000
#define NP 96
#define TOPM 20
#define MAXCH 128

// ---------------------------------------------------------------------------
// Kernel A: per-(b,c) multi-period stats -> normalized q [G,B,C,4] (fp64)
// lane = c, block = b. Coalesced loads (64 lanes read 256B contiguous).
// ---------------------------------------------------------------------------
__global__ __launch_bounds__(64) void qstat_kernel(const float* __restrict__ x,
                                                   double* __restrict__ q) {
  const int b = blockIdx.x;
  const int c = threadIdx.x;
  const float* xp = x + (size_t)b * NL * NC + c;
  double sum[3] = {0, 0, 0}, sumsq[3] = {0, 0, 0}, sumabs[3] = {0, 0, 0};
  double first[3] = {0, 0, 0}, prev[3] = {0, 0, 0};
  double acc2 = 0.0, acc4 = 0.0;
  for (int l = 0; l < NL; ++l) {
    double v = (double)xp[l * NC];
    {  // period 1 -> g index 2 (PERIODS=[4,2,1])
      sum[2] += v; sumsq[2] += v * v;
      if (l == 0) first[2] = v; else sumabs[2] += fabs(v - prev[2]);
      prev[2] = v;
    }
    acc2 += v;
    if ((l & 1) == 1) {  // period 2 -> g index 1
      double cur = acc2 * 0.5; acc2 = 0.0;
      sum[1] += cur; sumsq[1] += cur * cur;
      if ((l >> 1) == 0) first[1] = cur; else sumabs[1] += fabs(cur - prev[1]);
      prev[1] = cur;
    }
    acc4 += v;
    if ((l & 3) == 3) {  // period 4 -> g index 0
      double cur = acc4 * 0.25; acc4 = 0.0;
      if ((l >> 2) == 0) first[0] = cur; else sumabs[0] += fabs(cur - prev[0]);
      sum[0] += cur; sumsq[0] += cur * cur;
      prev[0] = cur;
    }
  }
  const double J[3] = {128.0, 256.0, 512.0};
  for (int g = 0; g < 3; ++g) {
    double mean = sum[g] / J[g];
    double var = sumsq[g] / J[g] - mean * mean;
    if (var < 0.0) var = 0.0;
    double s0 = mean - prev[g];
    double s1 = sqrt(var);
    double s2 = (prev[g] - first[g]) * (1.0 / 511.0);
    double s3 = sumabs[g] * (1.0 / 511.0);
    double n = sqrt(s0 * s0 + s1 * s1 + s2 * s2 + s3 * s3);
    double inv = 1.0 / fmax(n, 1e-12);
    double* qp = q + ((((size_t)g * NB) + b) * NC + c) * 4;
    qp[0] = s0 * inv; qp[1] = s1 * inv; qp[2] = s2 * inv; qp[3] = s3 * inv;
  }
}

// ---------------------------------------------------------------------------
// Kernel P: normalize pool_state once -> phat[t][c][12] fp64 (g-concatenated).
// Removes all sqrt/div from the sim inner loop.
// ---------------------------------------------------------------------------
__global__ __launch_bounds__(256) void pnorm_kernel(const float* __restrict__ ps,
                                                    double* __restrict__ phat) {
  const int i = blockIdx.x * 256 + threadIdx.x;  // over T*C
  if (i >= NT * NC) return;
  const int t = i >> 6, c = i & 63;
  double o[12];
#pragma unroll
  for (int g = 0; g < 3; ++g) {
    const float4 pv = *reinterpret_cast<const float4*>(
        ps + ((((size_t)g * NT) + t) * NC + c) * 4);
    double p0 = pv.x, p1 = pv.y, p2 = pv.z, p3 = pv.w;
    double n = sqrt(p0 * p0 + p1 * p1 + p2 * p2 + p3 * p3);
    double inv = 1.0 / fmax(n, 1e-12);
    o[g * 4 + 0] = p0 * inv; o[g * 4 + 1] = p1 * inv;
    o[g * 4 + 2] = p2 * inv; o[g * 4 + 3] = p3 * inv;
  }
  double2* op = reinterpret_cast<double2*>(phat + (size_t)i * 12);
#pragma unroll
  for (int j = 0; j < 6; ++j) op[j] = make_double2(o[2 * j], o[2 * j + 1]);
}

// ---------------------------------------------------------------------------
// Kernel B: 12-term fp64 dot + per-lane register top-20 over a t-chunk.
// lane = c; wave = one b (4 b's/block share the phat stream via L1).
// 1/3 (group mean) folded into qv. Gated unrolled carry-insertion.
// ---------------------------------------------------------------------------
__global__ __launch_bounds__(256, 3) void sim_topk_phat_kernel(
    const double* __restrict__ phat, const double* __restrict__ q,
    double* __restrict__ cval, int* __restrict__ cidx, int nch, int chunk) {
  const int wav = threadIdx.x >> 6;
  const int c = threadIdx.x & 63;
  const int b = blockIdx.y * 4 + wav;
  const int ch = blockIdx.x;
  double qv[12];
#pragma unroll
  for (int g = 0; g < 3; ++g) {
    const double* qp = q + ((((size_t)g * NB) + b) * NC + c) * 4;
#pragma unroll
    for (int j = 0; j < 4; ++j) qv[g * 4 + j] = qp[j] * (1.0 / 3.0);
  }
  double val[TOPM]; int idx[TOPM];
#pragma unroll
  for (int m = 0; m < TOPM; ++m) { val[m] = -1e300; idx[m] = 0; }
  int t0 = ch * chunk;
  int t1 = t0 + chunk; if (t1 > NT) t1 = NT;
  const double2* __restrict__ pp =
      reinterpret_cast<const double2*>(phat) + ((size_t)t0 * NC + c) * 6;
  const ptrdiff_t pstride = (ptrdiff_t)NC * 6;
  for (int t = t0; t < t1; ++t, pp += pstride) {
    const double2 a0 = pp[0], a1 = pp[1], a2 = pp[2];
    const double2 a3 = pp[3], a4 = pp[4], a5 = pp[5];
    double s = qv[0] * a0.x + qv[1] * a0.y + qv[2] * a1.x + qv[3] * a1.y +
               qv[4] * a2.x + qv[5] * a2.y + qv[6] * a3.x + qv[7] * a3.y +
               qv[8] * a4.x + qv[9] * a4.y + qv[10] * a5.x + qv[11] * a5.y;
    if (s > val[TOPM - 1]) {
      double cv = s; int ci = t;
#pragma unroll
      for (int m = 0; m < TOPM; ++m) {  // stable: ties keep lower t
        bool sw = cv > val[m];
        double tv = sw ? val[m] : cv; int ti = sw ? idx[m] : ci;
        val[m] = sw ? cv : val[m];    idx[m] = sw ? ci : idx[m];
        cv = tv; ci = ti;
      }
    }
  }
  double* vout = cval + ((((size_t)b * NC) + c) * nch + ch) * TOPM;
  int* iout = cidx + ((((size_t)b * NC) + c) * nch + ch) * TOPM;
#pragma unroll
  for (int m = 0; m < TOPM; ++m) { vout[m] = val[m]; iout[m] = idx[m]; }
}

// ---------------------------------------------------------------------------
// Kernel B': inline-normalize fallback (round-1 proven) if ws can't hold phat.
// ---------------------------------------------------------------------------
__global__ __launch_bounds__(256) void sim_topk_inline_kernel(
    const float* __restrict__ ps, const double* __restrict__ q,
    double* __restrict__ cval, int* __restrict__ cidx, int nch, int chunk) {
  const int wav = threadIdx.x >> 6;
  const int c = threadIdx.x & 63;
  const int b = blockIdx.y * 4 + wav;
  const int ch = blockIdx.x;
  double qv[3][4];
#pragma unroll
  for (int g = 0; g < 3; ++g) {
    const double* qp = q + ((((size_t)g * NB) + b) * NC + c) * 4;
    qv[g][0] = qp[0]; qv[g][1] = qp[1]; qv[g][2] = qp[2]; qv[g][3] = qp[3];
  }
  double val[TOPM]; int idx[TOPM];
#pragma unroll
  for (int m = 0; m < TOPM; ++m) { val[m] = -1e300; idx[m] = 0; }
  int t0 = ch * chunk;
  int t1 = t0 + chunk; if (t1 > NT) t1 = NT;
  for (int t = t0; t < t1; ++t) {
    double s = 0.0;
#pragma unroll
    for (int g = 0; g < 3; ++g) {
      const float4 pv = *reinterpret_cast<const float4*>(
          ps + ((((size_t)g * NT) + t) * NC + c) * 4);
      double p0 = pv.x, p1 = pv.y, p2 = pv.z, p3 = pv.w;
      double ss = p0 * p0 + p1 * p1 + p2 * p2 + p3 * p3;
      double dot = qv[g][0] * p0 + qv[g][1] * p1 + qv[g][2] * p2 + qv[g][3] * p3;
      s += dot / fmax(sqrt(ss), 1e-12);
    }
    s *= (1.0 / 3.0);
    if (s > val[TOPM - 1]) {
      double cv = s; int ci = t;
#pragma unroll
      for (int m = 0; m < TOPM; ++m) {
        bool sw = cv > val[m];
        double tv = sw ? val[m] : cv; int ti = sw ? idx[m] : ci;
        val[m] = sw ? cv : val[m];    idx[m] = sw ? ci : idx[m];
        cv = tv; ci = ti;
      }
    }
  }
  double* vout = cval + ((((size_t)b * NC) + c) * nch + ch) * TOPM;
  int* iout = cidx + ((((size_t)b * NC) + c) * nch + ch) * TOPM;
#pragma unroll
  for (int m = 0; m < TOPM; ++m) { vout[m] = val[m]; iout[m] = idx[m]; }
}

// ---------------------------------------------------------------------------
// Kernel C: LDS-staged merge of nch*20 sorted candidate lists -> top-20,
// softmax, gather. Cooperative load kills the serial L2-latency chain;
// per-chunk early break (lists sorted desc) kills the scan cost.
// ---------------------------------------------------------------------------
__global__ __launch_bounds__(128) void merge_gather_kernel(
    const double* __restrict__ cval, const int* __restrict__ cidx,
    const float* __restrict__ y, float* __restrict__ out, int nch) {
  const int c = blockIdx.x;
  const int b = blockIdx.y;
  __shared__ double v_s[MAXCH * TOPM];
  __shared__ int ix_s[MAXCH * TOPM];
  __shared__ float w_s[TOPM];
  __shared__ int i_s[TOPM];
  const int n = nch * TOPM;
  const double* vin = cval + (((size_t)b * NC) + c) * n;
  const int* iin = cidx + (((size_t)b * NC) + c) * n;
  for (int k = threadIdx.x; k < n; k += 128) { v_s[k] = vin[k]; ix_s[k] = iin[k]; }
  __syncthreads();
  if (threadIdx.x == 0) {
    double val[TOPM]; int idx[TOPM];
#pragma unroll
    for (int m = 0; m < TOPM; ++m) { val[m] = -1e300; idx[m] = 0; }
    for (int k = 0; k < nch; ++k) {
      const int base = k * TOPM;
      for (int m = 0; m < TOPM; ++m) {
        double s = v_s[base + m];
        if (!(s > val[TOPM - 1])) break;  // rest of chunk can't enter
        double cv = s; int ci = ix_s[base + m];
#pragma unroll
        for (int mm = 0; mm < TOPM; ++mm) {
          bool sw = cv > val[mm];
          double tv = sw ? val[mm] : cv; int ti = sw ? idx[mm] : ci;
          val[mm] = sw ? cv : val[mm];   idx[mm] = sw ? ci : idx[mm];
          cv = tv; ci = ti;
        }
      }
    }
    double mx = val[0];
    double e[TOPM]; double sum = 0.0;
#pragma unroll
    for (int m = 0; m < TOPM; ++m) { e[m] = exp((val[m] - mx) * 10.0); sum += e[m]; }
    double inv = 1.0 / sum;
#pragma unroll
    for (int m = 0; m < TOPM; ++m) { w_s[m] = (float)(e[m] * inv); i_s[m] = idx[m]; }
  }
  __syncthreads();
  const int p = threadIdx.x;
  if (p < NP) {
    float acc = 0.f;
#pragma unroll
    for (int m = 0; m < TOPM; ++m)
      acc += w_s[m] * y[(((size_t)i_s[m]) * NP + p) * NC + c];
    out[(((size_t)b * NP) + p) * NC + c] = acc;
  }
}

extern "C" void kernel_launch(void* const* d_in, const int* in_sizes, int n_in,
                              void* d_out, int out_size, void* d_ws, size_t ws_size,
                              hipStream_t stream) {
  const float* x = (const float*)d_in[0];
  const float* ps = (const float*)d_in[1];
  const float* y = (const float*)d_in[2];
  float* out = (float*)d_out;
  char* ws = (char*)d_ws;

  const size_t qbytes = (size_t)NG * NB * NC * 4 * sizeof(double);       // 196,608
  const size_t phatbytes = (size_t)NT * NC * 12 * sizeof(double);        // 61.44 MB
  const size_t per_ch = (size_t)NB * NC * TOPM * (sizeof(double) + sizeof(int));

  double* qbuf = (double*)ws;
  qstat_kernel<<<dim3(NB), dim3(NC), 0, stream>>>(x, qbuf);

  if (ws_size >= qbytes + phatbytes + 16 * per_ch) {
    // phat path
    size_t mc = (ws_size - qbytes - phatbytes) / per_ch;
    int nch = mc < MAXCH ? (int)mc : MAXCH;
    int chunk = (NT + nch - 1) / nch;
    double* phat = (double*)(ws + qbytes);
    double* cval = (double*)(ws + qbytes + phatbytes);
    int* cidx = (int*)((char*)cval + (size_t)NB * NC * nch * TOPM * sizeof(double));
    pnorm_kernel<<<dim3((NT * NC + 255) / 256), dim3(256), 0, stream>>>(ps, phat);
    sim_topk_phat_kernel<<<dim3(nch, NB / 4), dim3(256), 0, stream>>>(
        phat, qbuf, cval, cidx, nch, chunk);
    merge_gather_kernel<<<dim3(NC, NB), dim3(128), 0, stream>>>(cval, cidx, y, out, nch);
  } else {
    // fallback: inline normalization (round-1 proven)
    int nch = 1;
    if (ws_size > qbytes) {
      size_t mc = (ws_size - qbytes) / per_ch;
      nch = mc < MAXCH ? (int)mc : MAXCH;
      if (nch < 1) nch = 1;
    }
    int chunk = (NT + nch - 1) / nch;
    double* cval = (double*)(ws + qbytes);
    int* cidx = (int*)((char*)cval + (size_t)NB * NC * nch * TOPM * sizeof(double));
    sim_topk_inline_kernel<<<dim3(nch, NB / 4), dim3(256), 0, stream>>>(
        ps, qbuf, cval, cidx, nch, chunk);
    merge_gather_kernel<<<dim3(NC, NB), dim3(128), 0, stream>>>(cval, cidx, y, out, nch);
  }
}

// Round 3
// 380.099 us; speedup vs baseline: 1.7704x; 1.7704x over previous
//
#include <hip/hip_runtime.h>
#include <math.h>
#include <float.h>

#define NB 32
#define NL 512
#define NC 64
#define NG 3
#define NT 10000
#define NP 96
#define TOPM 20
#define M1 8      // per-lane per-chunk fp32 prefilter list
#define M2 24     // per-row fp32 candidate list (fp64 re-ranked -> top-20)
#define NCH 128   // t-chunks for sim32
#define GSTR ((size_t)NT * NC * 4)  // float stride between g-planes

// ---------------------------------------------------------------------------
// Kernel A: per-(b,c) multi-period stats -> normalized q [G,B,C,4] (fp64).
// lane = c, block = b. Coalesced (64 lanes read 256B contiguous per l).
// ---------------------------------------------------------------------------
__global__ __launch_bounds__(64) void qstat_kernel(const float* __restrict__ x,
                                                   double* __restrict__ q) {
  const int b = blockIdx.x;
  const int c = threadIdx.x;
  const float* xp = x + (size_t)b * NL * NC + c;
  double sum[3] = {0, 0, 0}, sumsq[3] = {0, 0, 0}, sumabs[3] = {0, 0, 0};
  double first[3] = {0, 0, 0}, prev[3] = {0, 0, 0};
  double acc2 = 0.0, acc4 = 0.0;
  for (int l = 0; l < NL; ++l) {
    double v = (double)xp[l * NC];
    {  // period 1 -> g index 2 (PERIODS=[4,2,1])
      sum[2] += v; sumsq[2] += v * v;
      if (l == 0) first[2] = v; else sumabs[2] += fabs(v - prev[2]);
      prev[2] = v;
    }
    acc2 += v;
    if ((l & 1) == 1) {
      double cur = acc2 * 0.5; acc2 = 0.0;
      sum[1] += cur; sumsq[1] += cur * cur;
      if ((l >> 1) == 0) first[1] = cur; else sumabs[1] += fabs(cur - prev[1]);
      prev[1] = cur;
    }
    acc4 += v;
    if ((l & 3) == 3) {
      double cur = acc4 * 0.25; acc4 = 0.0;
      if ((l >> 2) == 0) first[0] = cur; else sumabs[0] += fabs(cur - prev[0]);
      sum[0] += cur; sumsq[0] += cur * cur;
      prev[0] = cur;
    }
  }
  const double J[3] = {128.0, 256.0, 512.0};
  for (int g = 0; g < 3; ++g) {
    double mean = sum[g] / J[g];
    double var = sumsq[g] / J[g] - mean * mean;
    if (var < 0.0) var = 0.0;
    double s0 = mean - prev[g];
    double s1 = sqrt(var);
    double s2 = (prev[g] - first[g]) * (1.0 / 511.0);
    double s3 = sumabs[g] * (1.0 / 511.0);
    double n = sqrt(s0 * s0 + s1 * s1 + s2 * s2 + s3 * s3);
    double inv = 1.0 / fmax(n, 1e-12);
    double* qp = q + ((((size_t)g * NB) + b) * NC + c) * 4;
    qp[0] = s0 * inv; qp[1] = s1 * inv; qp[2] = s2 * inv; qp[3] = s3 * inv;
  }
}

// ---------------------------------------------------------------------------
// Kernel P: normalize pool_state -> fp32 phat, SAME [g][t][c][4] layout.
// float4 in, float4 out: fully coalesced both directions.
// ---------------------------------------------------------------------------
__global__ __launch_bounds__(256) void pnorm32_kernel(const float* __restrict__ ps,
                                                      float* __restrict__ phat) {
  const int i = blockIdx.x * 256 + threadIdx.x;  // over T*C
  if (i >= NT * NC) return;
  const int t = i >> 6, c = i & 63;
#pragma unroll
  for (int g = 0; g < 3; ++g) {
    const size_t off = ((((size_t)g * NT) + t) * NC + c) * 4;
    const float4 pv = *reinterpret_cast<const float4*>(ps + off);
    double p0 = pv.x, p1 = pv.y, p2 = pv.z, p3 = pv.w;
    double inv = 1.0 / fmax(sqrt(p0 * p0 + p1 * p1 + p2 * p2 + p3 * p3), 1e-12);
    float4 o;
    o.x = (float)(p0 * inv); o.y = (float)(p1 * inv);
    o.z = (float)(p2 * inv); o.w = (float)(p3 * inv);
    *reinterpret_cast<float4*>(phat + off) = o;
  }
}

__device__ __forceinline__ void insert8(float s, int ti, float val[M1], int idx[M1]) {
  float cv = s; int ci = ti;
#pragma unroll
  for (int m = 0; m < M1; ++m) {
    bool sw = cv > val[m];
    float tv = sw ? val[m] : cv; int tx = sw ? idx[m] : ci;
    val[m] = sw ? cv : val[m];   idx[m] = sw ? ci : idx[m];
    cv = tv; ci = tx;
  }
}

// ---------------------------------------------------------------------------
// Kernel B: fp32 prefilter scan. lane = c, wave = b (4 b/block share phat
// stream via L1). 12-term fp32 dot, 2-t ILP, gated top-8 insert per chunk.
// ---------------------------------------------------------------------------
__global__ __launch_bounds__(256) void sim32_kernel(
    const float* __restrict__ phat, const double* __restrict__ q,
    float* __restrict__ cval, int* __restrict__ cidx, int nch, int chunk) {
  const int wav = threadIdx.x >> 6;
  const int c = threadIdx.x & 63;
  const int b = blockIdx.y * 4 + wav;
  const int ch = blockIdx.x;
  float qv[12];
#pragma unroll
  for (int g = 0; g < 3; ++g) {
    const double* qp = q + ((((size_t)g * NB) + b) * NC + c) * 4;
#pragma unroll
    for (int j = 0; j < 4; ++j) qv[g * 4 + j] = (float)(qp[j] * (1.0 / 3.0));
  }
  float val[M1]; int idx[M1];
#pragma unroll
  for (int m = 0; m < M1; ++m) { val[m] = -1e30f; idx[m] = 0; }
  int t0 = ch * chunk;
  int t1 = t0 + chunk; if (t1 > NT) t1 = NT;
  int t = t0;
  for (; t + 1 < t1; t += 2) {
    const size_t oA = ((size_t)t * NC + c) * 4;
    const size_t oB = ((size_t)(t + 1) * NC + c) * 4;
    const float4 a0 = *reinterpret_cast<const float4*>(phat + oA);
    const float4 a1 = *reinterpret_cast<const float4*>(phat + GSTR + oA);
    const float4 a2 = *reinterpret_cast<const float4*>(phat + 2 * GSTR + oA);
    const float4 b0 = *reinterpret_cast<const float4*>(phat + oB);
    const float4 b1 = *reinterpret_cast<const float4*>(phat + GSTR + oB);
    const float4 b2 = *reinterpret_cast<const float4*>(phat + 2 * GSTR + oB);
    float sA = qv[0] * a0.x + qv[1] * a0.y + qv[2] * a0.z + qv[3] * a0.w +
               qv[4] * a1.x + qv[5] * a1.y + qv[6] * a1.z + qv[7] * a1.w +
               qv[8] * a2.x + qv[9] * a2.y + qv[10] * a2.z + qv[11] * a2.w;
    float sB = qv[0] * b0.x + qv[1] * b0.y + qv[2] * b0.z + qv[3] * b0.w +
               qv[4] * b1.x + qv[5] * b1.y + qv[6] * b1.z + qv[7] * b1.w +
               qv[8] * b2.x + qv[9] * b2.y + qv[10] * b2.z + qv[11] * b2.w;
    if (sA > val[M1 - 1]) insert8(sA, t, val, idx);
    if (sB > val[M1 - 1]) insert8(sB, t + 1, val, idx);
  }
  if (t < t1) {
    const size_t oA = ((size_t)t * NC + c) * 4;
    const float4 a0 = *reinterpret_cast<const float4*>(phat + oA);
    const float4 a1 = *reinterpret_cast<const float4*>(phat + GSTR + oA);
    const float4 a2 = *reinterpret_cast<const float4*>(phat + 2 * GSTR + oA);
    float sA = qv[0] * a0.x + qv[1] * a0.y + qv[2] * a0.z + qv[3] * a0.w +
               qv[4] * a1.x + qv[5] * a1.y + qv[6] * a1.z + qv[7] * a1.w +
               qv[8] * a2.x + qv[9] * a2.y + qv[10] * a2.z + qv[11] * a2.w;
    if (sA > val[M1 - 1]) insert8(sA, t, val, idx);
  }
  float* vo = cval + ((((size_t)b * NC) + c) * nch + ch) * M1;
  int* io = cidx + ((((size_t)b * NC) + c) * nch + ch) * M1;
#pragma unroll
  for (int m = 0; m < M1; ++m) { vo[m] = val[m]; io[m] = idx[m]; }
}

// ---------------------------------------------------------------------------
// Kernel C: fused merge (fp32 top-24) + fp64 re-rank (round-1-proven math)
// + top-20 select + softmax + gather. Block = (c,b), 128 threads.
// ---------------------------------------------------------------------------
__global__ __launch_bounds__(128) void merge_rerank_gather_kernel(
    const float* __restrict__ cval, const int* __restrict__ cidx,
    const float* __restrict__ ps, const double* __restrict__ q,
    const float* __restrict__ y, float* __restrict__ out, int nch) {
  const int c = blockIdx.x;
  const int b = blockIdx.y;
  __shared__ float v_s[NCH * M1];
  __shared__ int ix_s[NCH * M1];
  __shared__ int cand_s[M2];
  __shared__ double rv_s[M2];
  __shared__ int rt_s[M2];
  __shared__ float w_s[TOPM];
  __shared__ int i_s[TOPM];
  const int n = nch * M1;
  const float* vin = cval + (((size_t)b * NC) + c) * n;
  const int* iin = cidx + (((size_t)b * NC) + c) * n;
  for (int k = threadIdx.x; k < n; k += 128) { v_s[k] = vin[k]; ix_s[k] = iin[k]; }
  __syncthreads();
  // merge -> fp32 top-24 (chunk lists sorted desc -> early break)
  if (threadIdx.x == 0) {
    float val[M2]; int idx[M2];
#pragma unroll
    for (int m = 0; m < M2; ++m) { val[m] = -1e38f; idx[m] = 0; }
    for (int k = 0; k < nch; ++k) {
      const int base = k * M1;
      for (int m = 0; m < M1; ++m) {
        float s = v_s[base + m];
        if (!(s > val[M2 - 1])) break;
        float cv = s; int ci = ix_s[base + m];
#pragma unroll
        for (int mm = 0; mm < M2; ++mm) {
          bool sw = cv > val[mm];
          float tv = sw ? val[mm] : cv; int ti = sw ? idx[mm] : ci;
          val[mm] = sw ? cv : val[mm]; idx[mm] = sw ? ci : idx[mm];
          cv = tv; ci = ti;
        }
      }
    }
#pragma unroll
    for (int m = 0; m < M2; ++m) cand_s[m] = idx[m];
  }
  __syncthreads();
  // fp64 re-score of the 24 candidates (identical arithmetic to round-1)
  if (threadIdx.x < M2) {
    const int t = cand_s[threadIdx.x];
    double s = 0.0;
#pragma unroll
    for (int g = 0; g < 3; ++g) {
      const double* qp = q + ((((size_t)g * NB) + b) * NC + c) * 4;
      const float4 pv = *reinterpret_cast<const float4*>(
          ps + ((((size_t)g * NT) + t) * NC + c) * 4);
      double p0 = pv.x, p1 = pv.y, p2 = pv.z, p3 = pv.w;
      double ss = p0 * p0 + p1 * p1 + p2 * p2 + p3 * p3;
      double dot = qp[0] * p0 + qp[1] * p1 + qp[2] * p2 + qp[3] * p3;
      s += dot / fmax(sqrt(ss), 1e-12);
    }
    s *= (1.0 / 3.0);
    rv_s[threadIdx.x] = s; rt_s[threadIdx.x] = t;
  }
  __syncthreads();
  // top-20 of 24 by (v desc, t asc) + softmax(v/0.1)
  if (threadIdx.x == 0) {
    bool used[M2];
#pragma unroll
    for (int m = 0; m < M2; ++m) used[m] = false;
    double sel_v[TOPM]; int sel_t[TOPM];
    for (int r = 0; r < TOPM; ++r) {
      int best = -1;
      for (int k = 0; k < M2; ++k) {
        if (used[k]) continue;
        if (best < 0 || rv_s[k] > rv_s[best] ||
            (rv_s[k] == rv_s[best] && rt_s[k] < rt_s[best])) best = k;
      }
      used[best] = true;
      sel_v[r] = rv_s[best]; sel_t[r] = rt_s[best];
    }
    double mx = sel_v[0], sum = 0.0, e[TOPM];
#pragma unroll
    for (int m = 0; m < TOPM; ++m) { e[m] = exp((sel_v[m] - mx) * 10.0); sum += e[m]; }
    double inv = 1.0 / sum;
#pragma unroll
    for (int m = 0; m < TOPM; ++m) { w_s[m] = (float)(e[m] * inv); i_s[m] = sel_t[m]; }
  }
  __syncthreads();
  const int p = threadIdx.x;
  if (p < NP) {
    float acc = 0.f;
#pragma unroll
    for (int m = 0; m < TOPM; ++m)
      acc += w_s[m] * y[(((size_t)i_s[m]) * NP + p) * NC + c];
    out[(((size_t)b * NP) + p) * NC + c] = acc;
  }
}

// ---------------------------------------------------------------------------
// Fallback (small ws): round-1-proven all-fp64 inline path.
// ---------------------------------------------------------------------------
__global__ __launch_bounds__(256) void sim_topk_inline_kernel(
    const float* __restrict__ ps, const double* __restrict__ q,
    double* __restrict__ cval, int* __restrict__ cidx, int nch, int chunk) {
  const int wav = threadIdx.x >> 6;
  const int c = threadIdx.x & 63;
  const int b = blockIdx.y * 4 + wav;
  const int ch = blockIdx.x;
  double qv[3][4];
#pragma unroll
  for (int g = 0; g < 3; ++g) {
    const double* qp = q + ((((size_t)g * NB) + b) * NC + c) * 4;
    qv[g][0] = qp[0]; qv[g][1] = qp[1]; qv[g][2] = qp[2]; qv[g][3] = qp[3];
  }
  double val[TOPM]; int idx[TOPM];
#pragma unroll
  for (int m = 0; m < TOPM; ++m) { val[m] = -1e300; idx[m] = 0; }
  int t0 = ch * chunk;
  int t1 = t0 + chunk; if (t1 > NT) t1 = NT;
  for (int t = t0; t < t1; ++t) {
    double s = 0.0;
#pragma unroll
    for (int g = 0; g < 3; ++g) {
      const float4 pv = *reinterpret_cast<const float4*>(
          ps + ((((size_t)g * NT) + t) * NC + c) * 4);
      double p0 = pv.x, p1 = pv.y, p2 = pv.z, p3 = pv.w;
      double ss = p0 * p0 + p1 * p1 + p2 * p2 + p3 * p3;
      double dot = qv[g][0] * p0 + qv[g][1] * p1 + qv[g][2] * p2 + qv[g][3] * p3;
      s += dot / fmax(sqrt(ss), 1e-12);
    }
    s *= (1.0 / 3.0);
    if (s > val[TOPM - 1]) {
      double cv = s; int ci = t;
#pragma unroll
      for (int m = 0; m < TOPM; ++m) {
        bool sw = cv > val[m];
        double tv = sw ? val[m] : cv; int ti = sw ? idx[m] : ci;
        val[m] = sw ? cv : val[m];    idx[m] = sw ? ci : idx[m];
        cv = tv; ci = ti;
      }
    }
  }
  double* vout = cval + ((((size_t)b * NC) + c) * nch + ch) * TOPM;
  int* iout = cidx + ((((size_t)b * NC) + c) * nch + ch) * TOPM;
#pragma unroll
  for (int m = 0; m < TOPM; ++m) { vout[m] = val[m]; iout[m] = idx[m]; }
}

__global__ __launch_bounds__(128) void merge_gather_old_kernel(
    const double* __restrict__ cval, const int* __restrict__ cidx,
    const float* __restrict__ y, float* __restrict__ out, int nch) {
  const int c = blockIdx.x;
  const int b = blockIdx.y;
  __shared__ float w_s[TOPM];
  __shared__ int i_s[TOPM];
  if (threadIdx.x == 0) {
    double val[TOPM]; int idx[TOPM];
#pragma unroll
    for (int m = 0; m < TOPM; ++m) { val[m] = -1e300; idx[m] = 0; }
    const double* vin = cval + (((size_t)b * NC) + c) * nch * TOPM;
    const int* iin = cidx + (((size_t)b * NC) + c) * nch * TOPM;
    for (int k = 0; k < nch; ++k) {
      const int base = k * TOPM;
      for (int m = 0; m < TOPM; ++m) {
        double s = vin[base + m];
        if (!(s > val[TOPM - 1])) break;
        double cv = s; int ci = iin[base + m];
#pragma unroll
        for (int mm = 0; mm < TOPM; ++mm) {
          bool sw = cv > val[mm];
          double tv = sw ? val[mm] : cv; int ti = sw ? idx[mm] : ci;
          val[mm] = sw ? cv : val[mm];   idx[mm] = sw ? ci : idx[mm];
          cv = tv; ci = ti;
        }
      }
    }
    double mx = val[0];
    double e[TOPM]; double sum = 0.0;
#pragma unroll
    for (int m = 0; m < TOPM; ++m) { e[m] = exp((val[m] - mx) * 10.0); sum += e[m]; }
    double inv = 1.0 / sum;
#pragma unroll
    for (int m = 0; m < TOPM; ++m) { w_s[m] = (float)(e[m] * inv); i_s[m] = idx[m]; }
  }
  __syncthreads();
  const int p = threadIdx.x;
  if (p < NP) {
    float acc = 0.f;
#pragma unroll
    for (int m = 0; m < TOPM; ++m)
      acc += w_s[m] * y[(((size_t)i_s[m]) * NP + p) * NC + c];
    out[(((size_t)b * NP) + p) * NC + c] = acc;
  }
}

extern "C" void kernel_launch(void* const* d_in, const int* in_sizes, int n_in,
                              void* d_out, int out_size, void* d_ws, size_t ws_size,
                              hipStream_t stream) {
  const float* x = (const float*)d_in[0];
  const float* ps = (const float*)d_in[1];
  const float* y = (const float*)d_in[2];
  float* out = (float*)d_out;
  char* ws = (char*)d_ws;

  const size_t qbytes = (size_t)NG * NB * NC * 4 * sizeof(double);   // 196,608
  const size_t phat32bytes = (size_t)NG * NT * NC * 4 * sizeof(float);  // 30.72 MB
  const size_t candbytes = (size_t)NB * NC * NCH * M1 * (sizeof(float) + sizeof(int));  // 16.8 MB

  double* qbuf = (double*)ws;
  qstat_kernel<<<dim3(NB), dim3(NC), 0, stream>>>(x, qbuf);

  if (ws_size >= qbytes + phat32bytes + candbytes) {
    float* phat = (float*)(ws + qbytes);
    float* cval = (float*)(ws + qbytes + phat32bytes);
    int* cidx = (int*)((char*)cval + (size_t)NB * NC * NCH * M1 * sizeof(float));
    const int chunk = (NT + NCH - 1) / NCH;  // 79
    pnorm32_kernel<<<dim3((NT * NC + 255) / 256), dim3(256), 0, stream>>>(ps, phat);
    sim32_kernel<<<dim3(NCH, NB / 4), dim3(256), 0, stream>>>(phat, qbuf, cval, cidx,
                                                              NCH, chunk);
    merge_rerank_gather_kernel<<<dim3(NC, NB), dim3(128), 0, stream>>>(
        cval, cidx, ps, qbuf, y, out, NCH);
  } else {
    // fallback: round-1-proven all-fp64 path
    const size_t per_ch = (size_t)NB * NC * TOPM * (sizeof(double) + sizeof(int));
    int nch = 1;
    if (ws_size > qbytes) {
      size_t mc = (ws_size - qbytes) / per_ch;
      nch = mc < 32 ? (int)mc : 32;
      if (nch < 1) nch = 1;
    }
    const int chunk = (NT + nch - 1) / nch;
    double* cval = (double*)(ws + qbytes);
    int* cidx = (int*)((char*)cval + (size_t)NB * NC * nch * TOPM * sizeof(double));
    sim_topk_inline_kernel<<<dim3(nch, NB / 4), dim3(256), 0, stream>>>(
        ps, qbuf, cval, cidx, nch, chunk);
    merge_gather_old_kernel<<<dim3(NC, NB), dim3(128), 0, stream>>>(cval, cidx, y, out, nch);
  }
}

// Round 4
// 234.867 us; speedup vs baseline: 2.8652x; 1.6184x over previous
//
#include <hip/hip_runtime.h>
#include <math.h>
#include <float.h>

#define NB 32
#define NL 512
#define NC 64
#define NG 3
#define NT 10000
#define NP 96
#define TOPM 20
#define M1 8      // per-lane per-chunk fp32 prefilter list
#define M2 24     // fp32 candidates re-ranked in fp64 -> top-20
#define NCH 128   // t-chunks for sim32
#define GSTR ((size_t)NT * NC * 4)  // float stride between g-planes

// ---------------------------------------------------------------------------
// Kernel A: per-(b,c) multi-period stats -> normalized q [G,B,C,4] (fp64).
// ---------------------------------------------------------------------------
__global__ __launch_bounds__(64) void qstat_kernel(const float* __restrict__ x,
                                                   double* __restrict__ q) {
  const int b = blockIdx.x;
  const int c = threadIdx.x;
  const float* xp = x + (size_t)b * NL * NC + c;
  double sum[3] = {0, 0, 0}, sumsq[3] = {0, 0, 0}, sumabs[3] = {0, 0, 0};
  double first[3] = {0, 0, 0}, prev[3] = {0, 0, 0};
  double acc2 = 0.0, acc4 = 0.0;
  for (int l = 0; l < NL; ++l) {
    double v = (double)xp[l * NC];
    {  // period 1 -> g index 2 (PERIODS=[4,2,1])
      sum[2] += v; sumsq[2] += v * v;
      if (l == 0) first[2] = v; else sumabs[2] += fabs(v - prev[2]);
      prev[2] = v;
    }
    acc2 += v;
    if ((l & 1) == 1) {
      double cur = acc2 * 0.5; acc2 = 0.0;
      sum[1] += cur; sumsq[1] += cur * cur;
      if ((l >> 1) == 0) first[1] = cur; else sumabs[1] += fabs(cur - prev[1]);
      prev[1] = cur;
    }
    acc4 += v;
    if ((l & 3) == 3) {
      double cur = acc4 * 0.25; acc4 = 0.0;
      if ((l >> 2) == 0) first[0] = cur; else sumabs[0] += fabs(cur - prev[0]);
      sum[0] += cur; sumsq[0] += cur * cur;
      prev[0] = cur;
    }
  }
  const double J[3] = {128.0, 256.0, 512.0};
  for (int g = 0; g < 3; ++g) {
    double mean = sum[g] / J[g];
    double var = sumsq[g] / J[g] - mean * mean;
    if (var < 0.0) var = 0.0;
    double s0 = mean - prev[g];
    double s1 = sqrt(var);
    double s2 = (prev[g] - first[g]) * (1.0 / 511.0);
    double s3 = sumabs[g] * (1.0 / 511.0);
    double n = sqrt(s0 * s0 + s1 * s1 + s2 * s2 + s3 * s3);
    double inv = 1.0 / fmax(n, 1e-12);
    double* qp = q + ((((size_t)g * NB) + b) * NC + c) * 4;
    qp[0] = s0 * inv; qp[1] = s1 * inv; qp[2] = s2 * inv; qp[3] = s3 * inv;
  }
}

// ---------------------------------------------------------------------------
// Kernel P: normalize pool_state -> fp32 phat, SAME [g][t][c][4] layout.
// ---------------------------------------------------------------------------
__global__ __launch_bounds__(256) void pnorm32_kernel(const float* __restrict__ ps,
                                                      float* __restrict__ phat) {
  const int i = blockIdx.x * 256 + threadIdx.x;  // over T*C
  if (i >= NT * NC) return;
  const int t = i >> 6, c = i & 63;
#pragma unroll
  for (int g = 0; g < 3; ++g) {
    const size_t off = ((((size_t)g * NT) + t) * NC + c) * 4;
    const float4 pv = *reinterpret_cast<const float4*>(ps + off);
    double p0 = pv.x, p1 = pv.y, p2 = pv.z, p3 = pv.w;
    double inv = 1.0 / fmax(sqrt(p0 * p0 + p1 * p1 + p2 * p2 + p3 * p3), 1e-12);
    float4 o;
    o.x = (float)(p0 * inv); o.y = (float)(p1 * inv);
    o.z = (float)(p2 * inv); o.w = (float)(p3 * inv);
    *reinterpret_cast<float4*>(phat + off) = o;
  }
}

__device__ __forceinline__ void insert8(float s, int ti, float val[M1], int idx[M1]) {
  float cv = s; int ci = ti;
#pragma unroll
  for (int m = 0; m < M1; ++m) {
    bool sw = cv > val[m];
    float tv = sw ? val[m] : cv; int tx = sw ? idx[m] : ci;
    val[m] = sw ? cv : val[m];   idx[m] = sw ? ci : idx[m];
    cv = tv; ci = tx;
  }
}

// ---------------------------------------------------------------------------
// Kernel B: fp32 prefilter scan. lane = c, wave = b. Grid (bg, ch) so the 8
// consecutive blocks stream the SAME phat chunk (L2 reuse).
// ---------------------------------------------------------------------------
__global__ __launch_bounds__(256) void sim32_kernel(
    const float* __restrict__ phat, const double* __restrict__ q,
    float* __restrict__ cval, int* __restrict__ cidx, int nch, int chunk) {
  const int wav = threadIdx.x >> 6;
  const int c = threadIdx.x & 63;
  const int b = blockIdx.x * 4 + wav;
  const int ch = blockIdx.y;
  float qv[12];
#pragma unroll
  for (int g = 0; g < 3; ++g) {
    const double* qp = q + ((((size_t)g * NB) + b) * NC + c) * 4;
#pragma unroll
    for (int j = 0; j < 4; ++j) qv[g * 4 + j] = (float)(qp[j] * (1.0 / 3.0));
  }
  float val[M1]; int idx[M1];
#pragma unroll
  for (int m = 0; m < M1; ++m) { val[m] = -1e30f; idx[m] = 0; }
  int t0 = ch * chunk;
  int t1 = t0 + chunk; if (t1 > NT) t1 = NT;
  int t = t0;
  for (; t + 1 < t1; t += 2) {
    const size_t oA = ((size_t)t * NC + c) * 4;
    const size_t oB = ((size_t)(t + 1) * NC + c) * 4;
    const float4 a0 = *reinterpret_cast<const float4*>(phat + oA);
    const float4 a1 = *reinterpret_cast<const float4*>(phat + GSTR + oA);
    const float4 a2 = *reinterpret_cast<const float4*>(phat + 2 * GSTR + oA);
    const float4 b0 = *reinterpret_cast<const float4*>(phat + oB);
    const float4 b1 = *reinterpret_cast<const float4*>(phat + GSTR + oB);
    const float4 b2 = *reinterpret_cast<const float4*>(phat + 2 * GSTR + oB);
    float sA = qv[0] * a0.x + qv[1] * a0.y + qv[2] * a0.z + qv[3] * a0.w +
               qv[4] * a1.x + qv[5] * a1.y + qv[6] * a1.z + qv[7] * a1.w +
               qv[8] * a2.x + qv[9] * a2.y + qv[10] * a2.z + qv[11] * a2.w;
    float sB = qv[0] * b0.x + qv[1] * b0.y + qv[2] * b0.z + qv[3] * b0.w +
               qv[4] * b1.x + qv[5] * b1.y + qv[6] * b1.z + qv[7] * b1.w +
               qv[8] * b2.x + qv[9] * b2.y + qv[10] * b2.z + qv[11] * b2.w;
    if (sA > val[M1 - 1]) insert8(sA, t, val, idx);
    if (sB > val[M1 - 1]) insert8(sB, t + 1, val, idx);
  }
  if (t < t1) {
    const size_t oA = ((size_t)t * NC + c) * 4;
    const float4 a0 = *reinterpret_cast<const float4*>(phat + oA);
    const float4 a1 = *reinterpret_cast<const float4*>(phat + GSTR + oA);
    const float4 a2 = *reinterpret_cast<const float4*>(phat + 2 * GSTR + oA);
    float sA = qv[0] * a0.x + qv[1] * a0.y + qv[2] * a0.z + qv[3] * a0.w +
               qv[4] * a1.x + qv[5] * a1.y + qv[6] * a1.z + qv[7] * a1.w +
               qv[8] * a2.x + qv[9] * a2.y + qv[10] * a2.z + qv[11] * a2.w;
    if (sA > val[M1 - 1]) insert8(sA, t, val, idx);
  }
  float* vo = cval + ((((size_t)b * NC) + c) * nch + ch) * M1;
  int* io = cidx + ((((size_t)b * NC) + c) * nch + ch) * M1;
#pragma unroll
  for (int m = 0; m < M1; ++m) { vo[m] = val[m]; io[m] = idx[m]; }
}

// ---------------------------------------------------------------------------
// Kernel C1: wave-parallel merge (fp32 top-24 via shfl argmax over per-lane
// sorted chunk lists) + fp64 re-rank (validated arithmetic) + top-20 select
// + softmax. One wave per (b,c) row. Outputs (w,t)[20] per row.
// ---------------------------------------------------------------------------
__global__ __launch_bounds__(64) void merge_rerank_kernel(
    const float* __restrict__ cval, const int* __restrict__ cidx,
    const float* __restrict__ ps, const double* __restrict__ q,
    float* __restrict__ w_out, int* __restrict__ t_out) {
  const int c = blockIdx.x;
  const int b = blockIdx.y;
  const int lane = threadIdx.x;
  __shared__ float v_s[NCH * M1];
  __shared__ int i_s[NCH * M1];
  const int n = NCH * M1;  // 1024
  const size_t row = (size_t)b * NC + c;
  const float* vin = cval + row * n;
  const int* iin = cidx + row * n;
  for (int k = lane; k < n / 4; k += 64) {
    *reinterpret_cast<float4*>(&v_s[k * 4]) = reinterpret_cast<const float4*>(vin)[k];
    *reinterpret_cast<int4*>(&i_s[k * 4]) = reinterpret_cast<const int4*>(iin)[k];
  }
  __syncthreads();
  // lane owns two sorted-desc 8-lists: [lane*16, +8) and [lane*16+8, +8)
  const int baseA = lane * 16, baseB = lane * 16 + 8;
  int pa = 0, pb = 0;
  float va = v_s[baseA], vb = v_s[baseB];
  int ta = i_s[baseA], tb = i_s[baseB];
  float cv24 = 0.f; int ct24 = 0;  // lanes 0..23 collect candidates
  for (int r = 0; r < M2; ++r) {
    bool useA = (va > vb) || (va == vb && ta < tb);
    float v = useA ? va : vb;
    int tt = useA ? ta : tb;
    int o = lane;
#pragma unroll
    for (int st = 1; st < 64; st <<= 1) {
      float v2 = __shfl_xor(v, st);
      int t2 = __shfl_xor(tt, st);
      int o2 = __shfl_xor(o, st);
      bool take = (v2 > v) || (v2 == v && (t2 < tt || (t2 == tt && o2 < o)));
      v = take ? v2 : v; tt = take ? t2 : tt; o = take ? o2 : o;
    }
    if (lane == r) { cv24 = v; ct24 = tt; }
    if (lane == o) {
      if (useA) {
        ++pa;
        va = (pa < M1) ? v_s[baseA + pa] : -1e38f;
        ta = (pa < M1) ? i_s[baseA + pa] : 0x7fffffff;
      } else {
        ++pb;
        vb = (pb < M1) ? v_s[baseB + pb] : -1e38f;
        tb = (pb < M1) ? i_s[baseB + pb] : 0x7fffffff;
      }
    }
  }
  // fp64 re-score (identical arithmetic to validated path) on lanes 0..23
  double sv = -1e300; int st_ = 0x7fffffff;
  if (lane < M2) {
    const int t = ct24;
    double s = 0.0;
#pragma unroll
    for (int g = 0; g < 3; ++g) {
      const double* qp = q + ((((size_t)g * NB) + b) * NC + c) * 4;
      const float4 pv = *reinterpret_cast<const float4*>(
          ps + ((((size_t)g * NT) + t) * NC + c) * 4);
      double p0 = pv.x, p1 = pv.y, p2 = pv.z, p3 = pv.w;
      double ss = p0 * p0 + p1 * p1 + p2 * p2 + p3 * p3;
      double dot = qp[0] * p0 + qp[1] * p1 + qp[2] * p2 + qp[3] * p3;
      s += dot / fmax(sqrt(ss), 1e-12);
    }
    s *= (1.0 / 3.0);
    sv = s; st_ = t;
  }
  // 20 rounds of wave argmax on (sv desc, t asc); softmax accumulation
  double m0 = 0.0;
  double my_e = 0.0; int my_t = 0;
  for (int r = 0; r < TOPM; ++r) {
    double v = sv; int tt = st_; int o = lane;
#pragma unroll
    for (int st = 1; st < 64; st <<= 1) {
      double v2 = __shfl_xor(v, st);
      int t2 = __shfl_xor(tt, st);
      int o2 = __shfl_xor(o, st);
      bool take = (v2 > v) || (v2 == v && (t2 < tt || (t2 == tt && o2 < o)));
      v = take ? v2 : v; tt = take ? t2 : tt; o = take ? o2 : o;
    }
    if (r == 0) m0 = v;
    if (lane == r) { my_e = exp((v - m0) * 10.0); my_t = tt; }
    if (lane == o) { sv = -1e300; st_ = 0x7fffffff; }
  }
  double e = (lane < TOPM) ? my_e : 0.0;
#pragma unroll
  for (int st = 1; st < 64; st <<= 1) e += __shfl_xor(e, st);
  if (lane < TOPM) {
    w_out[row * TOPM + lane] = (float)(my_e / e);
    t_out[row * TOPM + lane] = my_t;
  }
}

// ---------------------------------------------------------------------------
// Kernel C2: pure gather. Block = (c,b); 96 active lanes, 20 independent
// scattered loads each.
// ---------------------------------------------------------------------------
__global__ __launch_bounds__(128) void gather_kernel(
    const float* __restrict__ w_in, const int* __restrict__ t_in,
    const float* __restrict__ y, float* __restrict__ out) {
  const int c = blockIdx.x;
  const int b = blockIdx.y;
  const size_t row = (size_t)b * NC + c;
  __shared__ float w_s[TOPM];
  __shared__ int t_s[TOPM];
  if (threadIdx.x < TOPM) {
    w_s[threadIdx.x] = w_in[row * TOPM + threadIdx.x];
    t_s[threadIdx.x] = t_in[row * TOPM + threadIdx.x];
  }
  __syncthreads();
  const int p = threadIdx.x;
  if (p < NP) {
    float acc = 0.f;
#pragma unroll
    for (int m = 0; m < TOPM; ++m)
      acc += w_s[m] * y[(((size_t)t_s[m]) * NP + p) * NC + c];
    out[(((size_t)b * NP) + p) * NC + c] = acc;
  }
}

// ---------------------------------------------------------------------------
// Fallback (small ws): round-1-proven all-fp64 inline path.
// ---------------------------------------------------------------------------
__global__ __launch_bounds__(256) void sim_topk_inline_kernel(
    const float* __restrict__ ps, const double* __restrict__ q,
    double* __restrict__ cval, int* __restrict__ cidx, int nch, int chunk) {
  const int wav = threadIdx.x >> 6;
  const int c = threadIdx.x & 63;
  const int b = blockIdx.y * 4 + wav;
  const int ch = blockIdx.x;
  double qv[3][4];
#pragma unroll
  for (int g = 0; g < 3; ++g) {
    const double* qp = q + ((((size_t)g * NB) + b) * NC + c) * 4;
    qv[g][0] = qp[0]; qv[g][1] = qp[1]; qv[g][2] = qp[2]; qv[g][3] = qp[3];
  }
  double val[TOPM]; int idx[TOPM];
#pragma unroll
  for (int m = 0; m < TOPM; ++m) { val[m] = -1e300; idx[m] = 0; }
  int t0 = ch * chunk;
  int t1 = t0 + chunk; if (t1 > NT) t1 = NT;
  for (int t = t0; t < t1; ++t) {
    double s = 0.0;
#pragma unroll
    for (int g = 0; g < 3; ++g) {
      const float4 pv = *reinterpret_cast<const float4*>(
          ps + ((((size_t)g * NT) + t) * NC + c) * 4);
      double p0 = pv.x, p1 = pv.y, p2 = pv.z, p3 = pv.w;
      double ss = p0 * p0 + p1 * p1 + p2 * p2 + p3 * p3;
      double dot = qv[g][0] * p0 + qv[g][1] * p1 + qv[g][2] * p2 + qv[g][3] * p3;
      s += dot / fmax(sqrt(ss), 1e-12);
    }
    s *= (1.0 / 3.0);
    if (s > val[TOPM - 1]) {
      double cv = s; int ci = t;
#pragma unroll
      for (int m = 0; m < TOPM; ++m) {
        bool sw = cv > val[m];
        double tv = sw ? val[m] : cv; int ti = sw ? idx[m] : ci;
        val[m] = sw ? cv : val[m];    idx[m] = sw ? ci : idx[m];
        cv = tv; ci = ti;
      }
    }
  }
  double* vout = cval + ((((size_t)b * NC) + c) * nch + ch) * TOPM;
  int* iout = cidx + ((((size_t)b * NC) + c) * nch + ch) * TOPM;
#pragma unroll
  for (int m = 0; m < TOPM; ++m) { vout[m] = val[m]; iout[m] = idx[m]; }
}

__global__ __launch_bounds__(128) void merge_gather_old_kernel(
    const double* __restrict__ cval, const int* __restrict__ cidx,
    const float* __restrict__ y, float* __restrict__ out, int nch) {
  const int c = blockIdx.x;
  const int b = blockIdx.y;
  __shared__ float w_s[TOPM];
  __shared__ int i_s[TOPM];
  if (threadIdx.x == 0) {
    double val[TOPM]; int idx[TOPM];
#pragma unroll
    for (int m = 0; m < TOPM; ++m) { val[m] = -1e300; idx[m] = 0; }
    const double* vin = cval + (((size_t)b * NC) + c) * nch * TOPM;
    const int* iin = cidx + (((size_t)b * NC) + c) * nch * TOPM;
    for (int k = 0; k < nch; ++k) {
      const int base = k * TOPM;
      for (int m = 0; m < TOPM; ++m) {
        double s = vin[base + m];
        if (!(s > val[TOPM - 1])) break;
        double cv = s; int ci = iin[base + m];
#pragma unroll
        for (int mm = 0; mm < TOPM; ++mm) {
          bool sw = cv > val[mm];
          double tv = sw ? val[mm] : cv; int ti = sw ? idx[mm] : ci;
          val[mm] = sw ? cv : val[mm];   idx[mm] = sw ? ci : idx[mm];
          cv = tv; ci = ti;
        }
      }
    }
    double mx = val[0];
    double e[TOPM]; double sum = 0.0;
#pragma unroll
    for (int m = 0; m < TOPM; ++m) { e[m] = exp((val[m] - mx) * 10.0); sum += e[m]; }
    double inv = 1.0 / sum;
#pragma unroll
    for (int m = 0; m < TOPM; ++m) { w_s[m] = (float)(e[m] * inv); i_s[m] = idx[m]; }
  }
  __syncthreads();
  const int p = threadIdx.x;
  if (p < NP) {
    float acc = 0.f;
#pragma unroll
    for (int m = 0; m < TOPM; ++m)
      acc += w_s[m] * y[(((size_t)i_s[m]) * NP + p) * NC + c];
    out[(((size_t)b * NP) + p) * NC + c] = acc;
  }
}

extern "C" void kernel_launch(void* const* d_in, const int* in_sizes, int n_in,
                              void* d_out, int out_size, void* d_ws, size_t ws_size,
                              hipStream_t stream) {
  const float* x = (const float*)d_in[0];
  const float* ps = (const float*)d_in[1];
  const float* y = (const float*)d_in[2];
  float* out = (float*)d_out;
  char* ws = (char*)d_ws;

  const size_t qbytes = (size_t)NG * NB * NC * 4 * sizeof(double);        // 196,608
  const size_t phat32bytes = (size_t)NG * NT * NC * 4 * sizeof(float);    // 30.72 MB
  const size_t cvalbytes = (size_t)NB * NC * NCH * M1 * sizeof(float);    // 8.39 MB
  const size_t cidxbytes = (size_t)NB * NC * NCH * M1 * sizeof(int);      // 8.39 MB
  const size_t wtbytes = (size_t)NB * NC * TOPM * (sizeof(float) + sizeof(int));  // 328 KB

  double* qbuf = (double*)ws;
  qstat_kernel<<<dim3(NB), dim3(NC), 0, stream>>>(x, qbuf);

  if (ws_size >= qbytes + phat32bytes + cvalbytes + cidxbytes + wtbytes) {
    float* phat = (float*)(ws + qbytes);
    float* cval = (float*)(ws + qbytes + phat32bytes);
    int* cidx = (int*)((char*)cval + cvalbytes);
    float* w_out = (float*)((char*)cidx + cidxbytes);
    int* t_out = (int*)((char*)w_out + (size_t)NB * NC * TOPM * sizeof(float));
    const int chunk = (NT + NCH - 1) / NCH;  // 79
    pnorm32_kernel<<<dim3((NT * NC + 255) / 256), dim3(256), 0, stream>>>(ps, phat);
    sim32_kernel<<<dim3(NB / 4, NCH), dim3(256), 0, stream>>>(phat, qbuf, cval, cidx,
                                                              NCH, chunk);
    merge_rerank_kernel<<<dim3(NC, NB), dim3(64), 0, stream>>>(cval, cidx, ps, qbuf,
                                                               w_out, t_out);
    gather_kernel<<<dim3(NC, NB), dim3(128), 0, stream>>>(w_out, t_out, y, out);
  } else {
    // fallback: round-1-proven all-fp64 path
    const size_t per_ch = (size_t)NB * NC * TOPM * (sizeof(double) + sizeof(int));
    int nch = 1;
    if (ws_size > qbytes) {
      size_t mc = (ws_size - qbytes) / per_ch;
      nch = mc < 32 ? (int)mc : 32;
      if (nch < 1) nch = 1;
    }
    const int chunk = (NT + nch - 1) / nch;
    double* cval = (double*)(ws + qbytes);
    int* cidx = (int*)((char*)cval + (size_t)NB * NC * nch * TOPM * sizeof(double));
    sim_topk_inline_kernel<<<dim3(nch, NB / 4), dim3(256), 0, stream>>>(
        ps, qbuf, cval, cidx, nch, chunk);
    merge_gather_old_kernel<<<dim3(NC, NB), dim3(128), 0, stream>>>(cval, cidx, y, out, nch);
  }
}

// Round 5
// 163.775 us; speedup vs baseline: 4.1089x; 1.4341x over previous
//
#include <hip/hip_runtime.h>
#include <math.h>

#define NB 32
#define NL 512
#define NC 64
#define NG 3
#define NT 10000
#define NP 96
#define TOPM 20
#define M1 8      // per-lane per-chunk fp32 prefilter list
#define M2 24     // fp32 candidates re-ranked in fp64 -> top-20
#define NCH 256   // t-chunks (250 real, 6 empty) -> 2048-entry rows, 8 waves/SIMD
#define CHUNK 40
#define GSTR ((size_t)NT * NC * 4)  // float stride between g-planes

// ---------------------------------------------------------------------------
// Kernel 1 (fused pre): blocks [0,NB) = qstat (8 waves over L-segments, LDS
// combine); blocks [NB,..) = pnorm32. Independent work, one launch.
// ---------------------------------------------------------------------------
__global__ __launch_bounds__(512) void pre_kernel(const float* __restrict__ x,
                                                  const float* __restrict__ ps,
                                                  double* __restrict__ q,
                                                  float* __restrict__ phat) {
  __shared__ double s_sum[8][3][64], s_sq[8][3][64], s_abs[8][3][64];
  __shared__ double s_first[3][64], s_last[3][64];
  if (blockIdx.x < NB) {
    const int b = blockIdx.x, w = threadIdx.x >> 6, c = threadIdx.x & 63;
    const float* xp = x + (size_t)b * NL * NC + c;
    const int l0 = w * 64;
    double sum[3] = {0, 0, 0}, sumsq[3] = {0, 0, 0}, sumabs[3] = {0, 0, 0};
    double prev[3] = {0, 0, 0}, first[3] = {0, 0, 0};
    if (w > 0) {  // seed prev-cur per period from 4 overlap elements
      double e0 = xp[(l0 - 4) * NC], e1 = xp[(l0 - 3) * NC];
      double e2 = xp[(l0 - 2) * NC], e3 = xp[(l0 - 1) * NC];
      prev[2] = e3; prev[1] = (e2 + e3) * 0.5; prev[0] = (e0 + e1 + e2 + e3) * 0.25;
    }
    double acc2 = 0.0, acc4 = 0.0;
    for (int i = 0; i < 64; ++i) {
      const int l = l0 + i;
      double v = (double)xp[l * NC];
      sum[2] += v; sumsq[2] += v * v;              // period 1 (g=2)
      if (l == 0) first[2] = v; else sumabs[2] += fabs(v - prev[2]);
      prev[2] = v;
      acc2 += v;
      if (l & 1) {                                  // period 2 (g=1)
        double cur = acc2 * 0.5; acc2 = 0.0;
        sum[1] += cur; sumsq[1] += cur * cur;
        if (l == 1) first[1] = cur; else sumabs[1] += fabs(cur - prev[1]);
        prev[1] = cur;
      }
      acc4 += v;
      if ((l & 3) == 3) {                           // period 4 (g=0)
        double cur = acc4 * 0.25; acc4 = 0.0;
        sum[0] += cur; sumsq[0] += cur * cur;
        if (l == 3) first[0] = cur; else sumabs[0] += fabs(cur - prev[0]);
        prev[0] = cur;
      }
    }
    for (int g = 0; g < 3; ++g) {
      s_sum[w][g][c] = sum[g]; s_sq[w][g][c] = sumsq[g]; s_abs[w][g][c] = sumabs[g];
    }
    if (w == 0) { for (int g = 0; g < 3; ++g) s_first[g][c] = first[g]; }
    if (w == 7) { for (int g = 0; g < 3; ++g) s_last[g][c] = prev[g]; }
    __syncthreads();
    if (w == 0) {
      const double J[3] = {128.0, 256.0, 512.0};
      for (int g = 0; g < 3; ++g) {
        double S = 0, Q2 = 0, A = 0;
        for (int ww = 0; ww < 8; ++ww) {
          S += s_sum[ww][g][c]; Q2 += s_sq[ww][g][c]; A += s_abs[ww][g][c];
        }
        double mean = S / J[g];
        double var = Q2 / J[g] - mean * mean; if (var < 0.0) var = 0.0;
        double last = s_last[g][c];
        double s0 = mean - last;
        double s1 = sqrt(var);
        double s2 = (last - s_first[g][c]) * (1.0 / 511.0);
        double s3 = A * (1.0 / 511.0);
        double n = sqrt(s0 * s0 + s1 * s1 + s2 * s2 + s3 * s3);
        double inv = 1.0 / fmax(n, 1e-12);
        double* qp = q + ((((size_t)g * NB) + b) * NC + c) * 4;
        qp[0] = s0 * inv; qp[1] = s1 * inv; qp[2] = s2 * inv; qp[3] = s3 * inv;
      }
    }
  } else {
    const int i = (blockIdx.x - NB) * 512 + threadIdx.x;  // over T*C
    if (i < NT * NC) {
      const int t = i >> 6, c = i & 63;
#pragma unroll
      for (int g = 0; g < 3; ++g) {
        const size_t off = ((((size_t)g * NT) + t) * NC + c) * 4;
        const float4 pv = *reinterpret_cast<const float4*>(ps + off);
        double p0 = pv.x, p1 = pv.y, p2 = pv.z, p3 = pv.w;
        double inv = 1.0 / fmax(sqrt(p0 * p0 + p1 * p1 + p2 * p2 + p3 * p3), 1e-12);
        float4 o;
        o.x = (float)(p0 * inv); o.y = (float)(p1 * inv);
        o.z = (float)(p2 * inv); o.w = (float)(p3 * inv);
        *reinterpret_cast<float4*>(phat + off) = o;
      }
    }
  }
}

__device__ __forceinline__ void insert8(float s, int ti, float val[M1], int idx[M1]) {
  float cv = s; int ci = ti;
#pragma unroll
  for (int m = 0; m < M1; ++m) {
    bool sw = cv > val[m];
    float tv = sw ? val[m] : cv; int tx = sw ? idx[m] : ci;
    val[m] = sw ? cv : val[m];   idx[m] = sw ? ci : idx[m];
    cv = tv; ci = tx;
  }
}

// ---------------------------------------------------------------------------
// Kernel 2: fp32 prefilter scan. lane = c, wave = b. NCH=256 chunks ->
// 8192 waves (8/SIMD); LB(256,8) keeps VGPR <= 64 (body measured 60).
// ---------------------------------------------------------------------------
__global__ __launch_bounds__(256, 8) void sim32_kernel(
    const float* __restrict__ phat, const double* __restrict__ q,
    float* __restrict__ cval, int* __restrict__ cidx) {
  const int wav = threadIdx.x >> 6;
  const int c = threadIdx.x & 63;
  const int b = blockIdx.x * 4 + wav;
  const int ch = blockIdx.y;
  float qv[12];
#pragma unroll
  for (int g = 0; g < 3; ++g) {
    const double* qp = q + ((((size_t)g * NB) + b) * NC + c) * 4;
#pragma unroll
    for (int j = 0; j < 4; ++j) qv[g * 4 + j] = (float)(qp[j] * (1.0 / 3.0));
  }
  float val[M1]; int idx[M1];
#pragma unroll
  for (int m = 0; m < M1; ++m) { val[m] = -1e30f; idx[m] = 0; }
  int t0 = ch * CHUNK;
  int t1 = t0 + CHUNK; if (t1 > NT) t1 = NT;
  for (int t = t0; t + 1 < t1; t += 2) {
    const size_t oA = ((size_t)t * NC + c) * 4;
    const size_t oB = ((size_t)(t + 1) * NC + c) * 4;
    const float4 a0 = *reinterpret_cast<const float4*>(phat + oA);
    const float4 a1 = *reinterpret_cast<const float4*>(phat + GSTR + oA);
    const float4 a2 = *reinterpret_cast<const float4*>(phat + 2 * GSTR + oA);
    const float4 b0 = *reinterpret_cast<const float4*>(phat + oB);
    const float4 b1 = *reinterpret_cast<const float4*>(phat + GSTR + oB);
    const float4 b2 = *reinterpret_cast<const float4*>(phat + 2 * GSTR + oB);
    float sA = qv[0] * a0.x + qv[1] * a0.y + qv[2] * a0.z + qv[3] * a0.w +
               qv[4] * a1.x + qv[5] * a1.y + qv[6] * a1.z + qv[7] * a1.w +
               qv[8] * a2.x + qv[9] * a2.y + qv[10] * a2.z + qv[11] * a2.w;
    float sB = qv[0] * b0.x + qv[1] * b0.y + qv[2] * b0.z + qv[3] * b0.w +
               qv[4] * b1.x + qv[5] * b1.y + qv[6] * b1.z + qv[7] * b1.w +
               qv[8] * b2.x + qv[9] * b2.y + qv[10] * b2.z + qv[11] * b2.w;
    if (sA > val[M1 - 1]) insert8(sA, t, val, idx);
    if (sB > val[M1 - 1]) insert8(sB, t + 1, val, idx);
  }
  float* vo = cval + ((((size_t)b * NC) + c) * NCH + ch) * M1;
  int* io = cidx + ((((size_t)b * NC) + c) * NCH + ch) * M1;
#pragma unroll
  for (int m = 0; m < M1; ++m) { vo[m] = val[m]; io[m] = idx[m]; }
}

// ---------------------------------------------------------------------------
// Kernel 3: fused merge (wave0: 4-list/lane shfl-argmax -> fp32 top-24) +
// fp64 re-rank (validated arithmetic) + top-20 + softmax -> LDS, then all
// 128 threads gather. Block = (c,b).
// ---------------------------------------------------------------------------
__global__ __launch_bounds__(128) void merge_gather_kernel(
    const float* __restrict__ cval, const int* __restrict__ cidx,
    const float* __restrict__ ps, const double* __restrict__ q,
    const float* __restrict__ y, float* __restrict__ out) {
  const int c = blockIdx.x, b = blockIdx.y;
  __shared__ float v_s[NCH * M1];
  __shared__ int i_s[NCH * M1];
  __shared__ float w_s[TOPM];
  __shared__ int t_s[TOPM];
  const int n = NCH * M1;  // 2048
  const size_t row = (size_t)b * NC + c;
  const float4* vin = reinterpret_cast<const float4*>(cval + row * n);
  const int4* iin = reinterpret_cast<const int4*>(cidx + row * n);
  for (int k = threadIdx.x; k < n / 4; k += 128) {
    *reinterpret_cast<float4*>(&v_s[k * 4]) = vin[k];
    *reinterpret_cast<int4*>(&i_s[k * 4]) = iin[k];
  }
  __syncthreads();
  if (threadIdx.x < 64) {
    const int lane = threadIdx.x;
    const int base = lane * 32;  // 4 sorted-desc 8-lists
    float hv0 = v_s[base], hv1 = v_s[base + 8], hv2 = v_s[base + 16], hv3 = v_s[base + 24];
    int ht0 = i_s[base], ht1 = i_s[base + 8], ht2 = i_s[base + 16], ht3 = i_s[base + 24];
    int p0_ = 0, p1_ = 0, p2_ = 0, p3_ = 0;
    int ct24 = 0;
    for (int r = 0; r < M2; ++r) {
      float bv = hv0; int bt = ht0; int bj = 0;
      if (hv1 > bv || (hv1 == bv && ht1 < bt)) { bv = hv1; bt = ht1; bj = 1; }
      if (hv2 > bv || (hv2 == bv && ht2 < bt)) { bv = hv2; bt = ht2; bj = 2; }
      if (hv3 > bv || (hv3 == bv && ht3 < bt)) { bv = hv3; bt = ht3; bj = 3; }
      float v = bv; int tt = bt; int o = lane;
#pragma unroll
      for (int st = 1; st < 64; st <<= 1) {
        float v2 = __shfl_xor(v, st);
        int t2 = __shfl_xor(tt, st);
        int o2 = __shfl_xor(o, st);
        bool take = (v2 > v) || (v2 == v && (t2 < tt || (t2 == tt && o2 < o)));
        v = take ? v2 : v; tt = take ? t2 : tt; o = take ? o2 : o;
      }
      if (lane == r) ct24 = tt;
      if (lane == o) {
        if (bj == 0) { ++p0_; hv0 = p0_ < M1 ? v_s[base + p0_] : -1e38f;
                       ht0 = p0_ < M1 ? i_s[base + p0_] : 0x7fffffff; }
        else if (bj == 1) { ++p1_; hv1 = p1_ < M1 ? v_s[base + 8 + p1_] : -1e38f;
                            ht1 = p1_ < M1 ? i_s[base + 8 + p1_] : 0x7fffffff; }
        else if (bj == 2) { ++p2_; hv2 = p2_ < M1 ? v_s[base + 16 + p2_] : -1e38f;
                            ht2 = p2_ < M1 ? i_s[base + 16 + p2_] : 0x7fffffff; }
        else { ++p3_; hv3 = p3_ < M1 ? v_s[base + 24 + p3_] : -1e38f;
               ht3 = p3_ < M1 ? i_s[base + 24 + p3_] : 0x7fffffff; }
      }
    }
    // fp64 re-score of the 24 candidates (identical arithmetic to validated path)
    double sv = -1e300; int st_ = 0x7fffffff;
    if (lane < M2) {
      const int t = ct24;
      double s = 0.0;
#pragma unroll
      for (int g = 0; g < 3; ++g) {
        const double* qp = q + ((((size_t)g * NB) + b) * NC + c) * 4;
        const float4 pv = *reinterpret_cast<const float4*>(
            ps + ((((size_t)g * NT) + t) * NC + c) * 4);
        double pp0 = pv.x, pp1 = pv.y, pp2 = pv.z, pp3 = pv.w;
        double ss = pp0 * pp0 + pp1 * pp1 + pp2 * pp2 + pp3 * pp3;
        double dot = qp[0] * pp0 + qp[1] * pp1 + qp[2] * pp2 + qp[3] * pp3;
        s += dot / fmax(sqrt(ss), 1e-12);
      }
      sv = s * (1.0 / 3.0); st_ = t;
    }
    // 20 rounds of wave argmax (v desc, t asc) + softmax
    double m0 = 0.0, my_e = 0.0; int my_t = 0;
    for (int r = 0; r < TOPM; ++r) {
      double v = sv; int tt = st_; int o = lane;
#pragma unroll
      for (int st = 1; st < 64; st <<= 1) {
        double v2 = __shfl_xor(v, st);
        int t2 = __shfl_xor(tt, st);
        int o2 = __shfl_xor(o, st);
        bool take = (v2 > v) || (v2 == v && (t2 < tt || (t2 == tt && o2 < o)));
        v = take ? v2 : v; tt = take ? t2 : tt; o = take ? o2 : o;
      }
      if (r == 0) m0 = v;
      if (lane == r) { my_e = exp((v - m0) * 10.0); my_t = tt; }
      if (lane == o) { sv = -1e300; st_ = 0x7fffffff; }
    }
    double e = (lane < TOPM) ? my_e : 0.0;
#pragma unroll
    for (int st = 1; st < 64; st <<= 1) e += __shfl_xor(e, st);
    if (lane < TOPM) { w_s[lane] = (float)(my_e / e); t_s[lane] = my_t; }
  }
  __syncthreads();
  const int p = threadIdx.x;
  if (p < NP) {
    float acc = 0.f;
#pragma unroll
    for (int m = 0; m < TOPM; ++m)
      acc += w_s[m] * y[(((size_t)t_s[m]) * NP + p) * NC + c];
    out[(((size_t)b * NP) + p) * NC + c] = acc;
  }
}

// ---------------------------------------------------------------------------
// Fallback (small ws): round-1-proven all-fp64 inline path.
// ---------------------------------------------------------------------------
__global__ __launch_bounds__(256) void sim_topk_inline_kernel(
    const float* __restrict__ ps, const double* __restrict__ q,
    double* __restrict__ cval, int* __restrict__ cidx, int nch, int chunk) {
  const int wav = threadIdx.x >> 6;
  const int c = threadIdx.x & 63;
  const int b = blockIdx.y * 4 + wav;
  const int ch = blockIdx.x;
  double qv[3][4];
#pragma unroll
  for (int g = 0; g < 3; ++g) {
    const double* qp = q + ((((size_t)g * NB) + b) * NC + c) * 4;
    qv[g][0] = qp[0]; qv[g][1] = qp[1]; qv[g][2] = qp[2]; qv[g][3] = qp[3];
  }
  double val[TOPM]; int idx[TOPM];
#pragma unroll
  for (int m = 0; m < TOPM; ++m) { val[m] = -1e300; idx[m] = 0; }
  int t0 = ch * chunk;
  int t1 = t0 + chunk; if (t1 > NT) t1 = NT;
  for (int t = t0; t < t1; ++t) {
    double s = 0.0;
#pragma unroll
    for (int g = 0; g < 3; ++g) {
      const float4 pv = *reinterpret_cast<const float4*>(
          ps + ((((size_t)g * NT) + t) * NC + c) * 4);
      double p0 = pv.x, p1 = pv.y, p2 = pv.z, p3 = pv.w;
      double ss = p0 * p0 + p1 * p1 + p2 * p2 + p3 * p3;
      double dot = qv[g][0] * p0 + qv[g][1] * p1 + qv[g][2] * p2 + qv[g][3] * p3;
      s += dot / fmax(sqrt(ss), 1e-12);
    }
    s *= (1.0 / 3.0);
    if (s > val[TOPM - 1]) {
      double cv = s; int ci = t;
#pragma unroll
      for (int m = 0; m < TOPM; ++m) {
        bool sw = cv > val[m];
        double tv = sw ? val[m] : cv; int ti = sw ? idx[m] : ci;
        val[m] = sw ? cv : val[m];    idx[m] = sw ? ci : idx[m];
        cv = tv; ci = ti;
      }
    }
  }
  double* vout = cval + ((((size_t)b * NC) + c) * nch + ch) * TOPM;
  int* iout = cidx + ((((size_t)b * NC) + c) * nch + ch) * TOPM;
#pragma unroll
  for (int m = 0; m < TOPM; ++m) { vout[m] = val[m]; iout[m] = idx[m]; }
}

__global__ __launch_bounds__(128) void merge_gather_old_kernel(
    const double* __restrict__ cval, const int* __restrict__ cidx,
    const float* __restrict__ y, float* __restrict__ out, int nch) {
  const int c = blockIdx.x;
  const int b = blockIdx.y;
  __shared__ float w_s[TOPM];
  __shared__ int i_s[TOPM];
  if (threadIdx.x == 0) {
    double val[TOPM]; int idx[TOPM];
#pragma unroll
    for (int m = 0; m < TOPM; ++m) { val[m] = -1e300; idx[m] = 0; }
    const double* vin = cval + (((size_t)b * NC) + c) * nch * TOPM;
    const int* iin = cidx + (((size_t)b * NC) + c) * nch * TOPM;
    for (int k = 0; k < nch; ++k) {
      const int base = k * TOPM;
      for (int m = 0; m < TOPM; ++m) {
        double s = vin[base + m];
        if (!(s > val[TOPM - 1])) break;
        double cv = s; int ci = iin[base + m];
#pragma unroll
        for (int mm = 0; mm < TOPM; ++mm) {
          bool sw = cv > val[mm];
          double tv = sw ? val[mm] : cv; int ti = sw ? idx[mm] : ci;
          val[mm] = sw ? cv : val[mm];   idx[mm] = sw ? ci : idx[mm];
          cv = tv; ci = ti;
        }
      }
    }
    double mx = val[0];
    double e[TOPM]; double sum = 0.0;
#pragma unroll
    for (int m = 0; m < TOPM; ++m) { e[m] = exp((val[m] - mx) * 10.0); sum += e[m]; }
    double inv = 1.0 / sum;
#pragma unroll
    for (int m = 0; m < TOPM; ++m) { w_s[m] = (float)(e[m] * inv); i_s[m] = idx[m]; }
  }
  __syncthreads();
  const int p = threadIdx.x;
  if (p < NP) {
    float acc = 0.f;
#pragma unroll
    for (int m = 0; m < TOPM; ++m)
      acc += w_s[m] * y[(((size_t)i_s[m]) * NP + p) * NC + c];
    out[(((size_t)b * NP) + p) * NC + c] = acc;
  }
}

extern "C" void kernel_launch(void* const* d_in, const int* in_sizes, int n_in,
                              void* d_out, int out_size, void* d_ws, size_t ws_size,
                              hipStream_t stream) {
  const float* x = (const float*)d_in[0];
  const float* ps = (const float*)d_in[1];
  const float* y = (const float*)d_in[2];
  float* out = (float*)d_out;
  char* ws = (char*)d_ws;

  const size_t qbytes = (size_t)NG * NB * NC * 4 * sizeof(double);        // 196,608
  const size_t phat32bytes = (size_t)NG * NT * NC * 4 * sizeof(float);    // 30.72 MB
  const size_t cvalbytes = (size_t)NB * NC * NCH * M1 * sizeof(float);    // 16.78 MB
  const size_t cidxbytes = (size_t)NB * NC * NCH * M1 * sizeof(int);      // 16.78 MB

  double* qbuf = (double*)ws;

  if (ws_size >= qbytes + phat32bytes + cvalbytes + cidxbytes) {
    float* phat = (float*)(ws + qbytes);
    float* cval = (float*)(ws + qbytes + phat32bytes);
    int* cidx = (int*)((char*)cval + cvalbytes);
    const int pn_blocks = (NT * NC + 511) / 512;  // 1250
    pre_kernel<<<dim3(NB + pn_blocks), dim3(512), 0, stream>>>(x, ps, qbuf, phat);
    sim32_kernel<<<dim3(NB / 4, NCH), dim3(256), 0, stream>>>(phat, qbuf, cval, cidx);
    merge_gather_kernel<<<dim3(NC, NB), dim3(128), 0, stream>>>(cval, cidx, ps, qbuf,
                                                                y, out);
  } else {
    // fallback: round-1-proven all-fp64 path (pre_kernel qstat part only)
    pre_kernel<<<dim3(NB), dim3(512), 0, stream>>>(x, ps, qbuf, (float*)nullptr);
    const size_t per_ch = (size_t)NB * NC * TOPM * (sizeof(double) + sizeof(int));
    int nch = 1;
    if (ws_size > qbytes) {
      size_t mc = (ws_size - qbytes) / per_ch;
      nch = mc < 32 ? (int)mc : 32;
      if (nch < 1) nch = 1;
    }
    const int chunk = (NT + nch - 1) / nch;
    double* cval = (double*)(ws + qbytes);
    int* cidx = (int*)((char*)cval + (size_t)NB * NC * nch * TOPM * sizeof(double));
    sim_topk_inline_kernel<<<dim3(nch, NB / 4), dim3(256), 0, stream>>>(
        ps, qbuf, cval, cidx, nch, chunk);
    merge_gather_old_kernel<<<dim3(NC, NB), dim3(128), 0, stream>>>(cval, cidx, y, out, nch);
  }
}

// Round 6
// 139.136 us; speedup vs baseline: 4.8365x; 1.1771x over previous
//
#include <hip/hip_runtime.h>
#include <math.h>

#define NB 32
#define NL 512
#define NC 64
#define NG 3
#define NT 10000
#define NP 96
#define TOPM 20
#define M1 8      // per-lane per-chunk fp32 prefilter list
#define NCH 256   // t-chunks (250 real, 6 empty)
#define CHUNK 40
#define QK 16     // extracted per quarter (4 quarters -> 64 candidates)
#define NCAND 64
#define GSTR ((size_t)NT * NC * 4)  // float stride between g-planes

// ---------------------------------------------------------------------------
// Kernel 1 (fused pre): blocks [0,NB) = qstat (8 waves over L-segments, LDS
// combine); blocks [NB,..) = pnorm32. (R5-proven, unchanged.)
// ---------------------------------------------------------------------------
__global__ __launch_bounds__(512) void pre_kernel(const float* __restrict__ x,
                                                  const float* __restrict__ ps,
                                                  double* __restrict__ q,
                                                  float* __restrict__ phat) {
  __shared__ double s_sum[8][3][64], s_sq[8][3][64], s_abs[8][3][64];
  __shared__ double s_first[3][64], s_last[3][64];
  if (blockIdx.x < NB) {
    const int b = blockIdx.x, w = threadIdx.x >> 6, c = threadIdx.x & 63;
    const float* xp = x + (size_t)b * NL * NC + c;
    const int l0 = w * 64;
    double sum[3] = {0, 0, 0}, sumsq[3] = {0, 0, 0}, sumabs[3] = {0, 0, 0};
    double prev[3] = {0, 0, 0}, first[3] = {0, 0, 0};
    if (w > 0) {
      double e0 = xp[(l0 - 4) * NC], e1 = xp[(l0 - 3) * NC];
      double e2 = xp[(l0 - 2) * NC], e3 = xp[(l0 - 1) * NC];
      prev[2] = e3; prev[1] = (e2 + e3) * 0.5; prev[0] = (e0 + e1 + e2 + e3) * 0.25;
    }
    double acc2 = 0.0, acc4 = 0.0;
    for (int i = 0; i < 64; ++i) {
      const int l = l0 + i;
      double v = (double)xp[l * NC];
      sum[2] += v; sumsq[2] += v * v;
      if (l == 0) first[2] = v; else sumabs[2] += fabs(v - prev[2]);
      prev[2] = v;
      acc2 += v;
      if (l & 1) {
        double cur = acc2 * 0.5; acc2 = 0.0;
        sum[1] += cur; sumsq[1] += cur * cur;
        if (l == 1) first[1] = cur; else sumabs[1] += fabs(cur - prev[1]);
        prev[1] = cur;
      }
      acc4 += v;
      if ((l & 3) == 3) {
        double cur = acc4 * 0.25; acc4 = 0.0;
        sum[0] += cur; sumsq[0] += cur * cur;
        if (l == 3) first[0] = cur; else sumabs[0] += fabs(cur - prev[0]);
        prev[0] = cur;
      }
    }
    for (int g = 0; g < 3; ++g) {
      s_sum[w][g][c] = sum[g]; s_sq[w][g][c] = sumsq[g]; s_abs[w][g][c] = sumabs[g];
    }
    if (w == 0) { for (int g = 0; g < 3; ++g) s_first[g][c] = first[g]; }
    if (w == 7) { for (int g = 0; g < 3; ++g) s_last[g][c] = prev[g]; }
    __syncthreads();
    if (w == 0) {
      const double J[3] = {128.0, 256.0, 512.0};
      for (int g = 0; g < 3; ++g) {
        double S = 0, Q2 = 0, A = 0;
        for (int ww = 0; ww < 8; ++ww) {
          S += s_sum[ww][g][c]; Q2 += s_sq[ww][g][c]; A += s_abs[ww][g][c];
        }
        double mean = S / J[g];
        double var = Q2 / J[g] - mean * mean; if (var < 0.0) var = 0.0;
        double last = s_last[g][c];
        double s0 = mean - last;
        double s1 = sqrt(var);
        double s2 = (last - s_first[g][c]) * (1.0 / 511.0);
        double s3 = A * (1.0 / 511.0);
        double n = sqrt(s0 * s0 + s1 * s1 + s2 * s2 + s3 * s3);
        double inv = 1.0 / fmax(n, 1e-12);
        double* qp = q + ((((size_t)g * NB) + b) * NC + c) * 4;
        qp[0] = s0 * inv; qp[1] = s1 * inv; qp[2] = s2 * inv; qp[3] = s3 * inv;
      }
    }
  } else {
    const int i = (blockIdx.x - NB) * 512 + threadIdx.x;  // over T*C
    if (i < NT * NC) {
      const int t = i >> 6, c = i & 63;
#pragma unroll
      for (int g = 0; g < 3; ++g) {
        const size_t off = ((((size_t)g * NT) + t) * NC + c) * 4;
        const float4 pv = *reinterpret_cast<const float4*>(ps + off);
        double p0 = pv.x, p1 = pv.y, p2 = pv.z, p3 = pv.w;
        double inv = 1.0 / fmax(sqrt(p0 * p0 + p1 * p1 + p2 * p2 + p3 * p3), 1e-12);
        float4 o;
        o.x = (float)(p0 * inv); o.y = (float)(p1 * inv);
        o.z = (float)(p2 * inv); o.w = (float)(p3 * inv);
        *reinterpret_cast<float4*>(phat + off) = o;
      }
    }
  }
}

__device__ __forceinline__ void insert8(float s, int ti, float val[M1], int idx[M1]) {
  float cv = s; int ci = ti;
#pragma unroll
  for (int m = 0; m < M1; ++m) {
    bool sw = cv > val[m];
    float tv = sw ? val[m] : cv; int tx = sw ? idx[m] : ci;
    val[m] = sw ? cv : val[m];   idx[m] = sw ? ci : idx[m];
    cv = tv; ci = tx;
  }
}

// ---------------------------------------------------------------------------
// Kernel 2: fp32 prefilter scan. 1024-thr blocks = 16 waves = 16 b's sharing
// one chunk stream (L1/L2 reuse; L3 traffic 246->61 MB). Grid (NB/16, NCH).
// 2 blocks/CU -> 8 waves/SIMD; body is the R5-proven 60-VGPR loop.
// ---------------------------------------------------------------------------
__global__ __launch_bounds__(1024, 8) void sim32_kernel(
    const float* __restrict__ phat, const double* __restrict__ q,
    float* __restrict__ cval, int* __restrict__ cidx) {
  const int wav = threadIdx.x >> 6;
  const int c = threadIdx.x & 63;
  const int b = blockIdx.x * 16 + wav;
  const int ch = blockIdx.y;
  float qv[12];
#pragma unroll
  for (int g = 0; g < 3; ++g) {
    const double* qp = q + ((((size_t)g * NB) + b) * NC + c) * 4;
#pragma unroll
    for (int j = 0; j < 4; ++j) qv[g * 4 + j] = (float)(qp[j] * (1.0 / 3.0));
  }
  float val[M1]; int idx[M1];
#pragma unroll
  for (int m = 0; m < M1; ++m) { val[m] = -1e30f; idx[m] = 0; }
  int t0 = ch * CHUNK;
  int t1 = t0 + CHUNK; if (t1 > NT) t1 = NT;
  for (int t = t0; t + 1 < t1; t += 2) {
    const size_t oA = ((size_t)t * NC + c) * 4;
    const size_t oB = ((size_t)(t + 1) * NC + c) * 4;
    const float4 a0 = *reinterpret_cast<const float4*>(phat + oA);
    const float4 a1 = *reinterpret_cast<const float4*>(phat + GSTR + oA);
    const float4 a2 = *reinterpret_cast<const float4*>(phat + 2 * GSTR + oA);
    const float4 b0 = *reinterpret_cast<const float4*>(phat + oB);
    const float4 b1 = *reinterpret_cast<const float4*>(phat + GSTR + oB);
    const float4 b2 = *reinterpret_cast<const float4*>(phat + 2 * GSTR + oB);
    float sA = qv[0] * a0.x + qv[1] * a0.y + qv[2] * a0.z + qv[3] * a0.w +
               qv[4] * a1.x + qv[5] * a1.y + qv[6] * a1.z + qv[7] * a1.w +
               qv[8] * a2.x + qv[9] * a2.y + qv[10] * a2.z + qv[11] * a2.w;
    float sB = qv[0] * b0.x + qv[1] * b0.y + qv[2] * b0.z + qv[3] * b0.w +
               qv[4] * b1.x + qv[5] * b1.y + qv[6] * b1.z + qv[7] * b1.w +
               qv[8] * b2.x + qv[9] * b2.y + qv[10] * b2.z + qv[11] * b2.w;
    if (sA > val[M1 - 1]) insert8(sA, t, val, idx);
    if (sB > val[M1 - 1]) insert8(sB, t + 1, val, idx);
  }
  float* vo = cval + ((((size_t)b * NC) + c) * NCH + ch) * M1;
  int* io = cidx + ((((size_t)b * NC) + c) * NCH + ch) * M1;
#pragma unroll
  for (int m = 0; m < M1; ++m) { vo[m] = val[m]; io[m] = idx[m]; }
}

// order-preserving fp32 -> u32 map; key = (v asc-map << 32) | (MAX - t)
// so u64-descending == (v desc, t asc). t < 2^32, unique per row => unique keys.
__device__ __forceinline__ unsigned long long mk_key(float v, int t) {
  unsigned u = __float_as_uint(v);
  u = (u & 0x80000000u) ? ~u : (u | 0x80000000u);
  return ((unsigned long long)u << 32) | (unsigned long long)(0xFFFFFFFFu - (unsigned)t);
}

// ---------------------------------------------------------------------------
// Kernel 3: merge + rerank + softmax + gather. Block = (c,b), 128 threads.
// 4 parallel 32-lane quarters each extract top-16 of 64 sorted chunk-lists
// via u64-key shfl argmax (16 rounds x 5 steps). 64 candidates fp64-rescored
// (validated arithmetic), ranked by counting (LDS broadcast), softmax,
// 96-lane gather.
// ---------------------------------------------------------------------------
__global__ __launch_bounds__(128) void merge_gather_kernel(
    const float* __restrict__ cval, const int* __restrict__ cidx,
    const float* __restrict__ ps, const double* __restrict__ q,
    const float* __restrict__ y, float* __restrict__ out) {
  const int c = blockIdx.x, b = blockIdx.y;
  __shared__ float v_s[NCH * M1];
  __shared__ int i_s[NCH * M1];
  __shared__ int ct_s[NCAND];
  __shared__ double rv_s[NCAND];
  __shared__ double m0_s, inv_s;
  __shared__ double e_s[TOPM];
  __shared__ float w_s[TOPM];
  __shared__ int ts_s[TOPM];
  const int n = NCH * M1;  // 2048
  const size_t row = (size_t)b * NC + c;
  const float4* vin = reinterpret_cast<const float4*>(cval + row * n);
  const int4* iin = reinterpret_cast<const int4*>(cidx + row * n);
  for (int k = threadIdx.x; k < n / 4; k += 128) {
    *reinterpret_cast<float4*>(&v_s[k * 4]) = vin[k];
    *reinterpret_cast<int4*>(&i_s[k * 4]) = iin[k];
  }
  __syncthreads();
  // --- quarter extraction: quarter = (wave<<1)|(lane>>5); 2 lists per lane ---
  {
    const int w = threadIdx.x >> 6, lane = threadIdx.x & 63;
    const int lane32 = lane & 31;
    const int qtr = (w << 1) | (lane >> 5);
    const int l0 = (qtr * 64 + lane32 * 2) * M1;  // list 0 base (sorted desc)
    const int l1 = l0 + M1;                       // list 1 base
    int p0 = 0, p1 = 0;
    unsigned long long k0 = mk_key(v_s[l0], i_s[l0]);
    unsigned long long k1 = mk_key(v_s[l1], i_s[l1]);
    for (int r = 0; r < QK; ++r) {
      unsigned long long me = k0 > k1 ? k0 : k1;
      unsigned long long km = me;
#pragma unroll
      for (int st = 1; st < 32; st <<= 1) {
        unsigned long long k2 = __shfl_xor(km, st);
        km = k2 > km ? k2 : km;
      }
      if (lane32 == r)
        ct_s[qtr * QK + r] = (int)(0xFFFFFFFFu - (unsigned)(km & 0xFFFFFFFFull));
      if (me == km) {  // unique keys -> exactly one owner
        if (k0 >= k1) {
          ++p0;
          k0 = (p0 < M1) ? mk_key(v_s[l0 + p0], i_s[l0 + p0]) : 0ull;
        } else {
          ++p1;
          k1 = (p1 < M1) ? mk_key(v_s[l1 + p1], i_s[l1 + p1]) : 0ull;
        }
      }
    }
  }
  __syncthreads();
  // --- fp64 re-score of 64 candidates (identical arithmetic to validated) ---
  if (threadIdx.x < NCAND) {
    const int t = ct_s[threadIdx.x];
    double s = 0.0;
#pragma unroll
    for (int g = 0; g < 3; ++g) {
      const double* qp = q + ((((size_t)g * NB) + b) * NC + c) * 4;
      const float4 pv = *reinterpret_cast<const float4*>(
          ps + ((((size_t)g * NT) + t) * NC + c) * 4);
      double pp0 = pv.x, pp1 = pv.y, pp2 = pv.z, pp3 = pv.w;
      double ss = pp0 * pp0 + pp1 * pp1 + pp2 * pp2 + pp3 * pp3;
      double dot = qp[0] * pp0 + qp[1] * pp1 + qp[2] * pp2 + qp[3] * pp3;
      s += dot / fmax(sqrt(ss), 1e-12);
    }
    rv_s[threadIdx.x] = s * (1.0 / 3.0);
  }
  __syncthreads();
  // --- rank by counting (v desc, t asc); ranks unique since t unique ---
  if (threadIdx.x < NCAND) {
    const double v = rv_s[threadIdx.x];
    const int t = ct_s[threadIdx.x];
    int rank = 0;
    for (int j = 0; j < NCAND; ++j) {
      double vj = rv_s[j]; int tj = ct_s[j];
      rank += (vj > v) || (vj == v && tj < t);
    }
    if (rank == 0) m0_s = v;
    __syncthreads();
    if (rank < TOPM) {
      e_s[rank] = exp((v - m0_s) * 10.0);
      ts_s[rank] = t;
    }
    __syncthreads();
    if (threadIdx.x == 0) {
      double sum = 0.0;
#pragma unroll
      for (int m = 0; m < TOPM; ++m) sum += e_s[m];
      inv_s = 1.0 / sum;
    }
    __syncthreads();
    if (threadIdx.x < TOPM) w_s[threadIdx.x] = (float)(e_s[threadIdx.x] * inv_s);
  } else {
    __syncthreads(); __syncthreads(); __syncthreads();
  }
  __syncthreads();
  // --- gather ---
  const int p = threadIdx.x;
  if (p < NP) {
    float acc = 0.f;
#pragma unroll
    for (int m = 0; m < TOPM; ++m)
      acc += w_s[m] * y[(((size_t)ts_s[m]) * NP + p) * NC + c];
    out[(((size_t)b * NP) + p) * NC + c] = acc;
  }
}

// ---------------------------------------------------------------------------
// Fallback (small ws): round-1-proven all-fp64 inline path.
// ---------------------------------------------------------------------------
__global__ __launch_bounds__(256) void sim_topk_inline_kernel(
    const float* __restrict__ ps, const double* __restrict__ q,
    double* __restrict__ cval, int* __restrict__ cidx, int nch, int chunk) {
  const int wav = threadIdx.x >> 6;
  const int c = threadIdx.x & 63;
  const int b = blockIdx.y * 4 + wav;
  const int ch = blockIdx.x;
  double qv[3][4];
#pragma unroll
  for (int g = 0; g < 3; ++g) {
    const double* qp = q + ((((size_t)g * NB) + b) * NC + c) * 4;
    qv[g][0] = qp[0]; qv[g][1] = qp[1]; qv[g][2] = qp[2]; qv[g][3] = qp[3];
  }
  double val[TOPM]; int idx[TOPM];
#pragma unroll
  for (int m = 0; m < TOPM; ++m) { val[m] = -1e300; idx[m] = 0; }
  int t0 = ch * chunk;
  int t1 = t0 + chunk; if (t1 > NT) t1 = NT;
  for (int t = t0; t < t1; ++t) {
    double s = 0.0;
#pragma unroll
    for (int g = 0; g < 3; ++g) {
      const float4 pv = *reinterpret_cast<const float4*>(
          ps + ((((size_t)g * NT) + t) * NC + c) * 4);
      double p0 = pv.x, p1 = pv.y, p2 = pv.z, p3 = pv.w;
      double ss = p0 * p0 + p1 * p1 + p2 * p2 + p3 * p3;
      double dot = qv[g][0] * p0 + qv[g][1] * p1 + qv[g][2] * p2 + qv[g][3] * p3;
      s += dot / fmax(sqrt(ss), 1e-12);
    }
    s *= (1.0 / 3.0);
    if (s > val[TOPM - 1]) {
      double cv = s; int ci = t;
#pragma unroll
      for (int m = 0; m < TOPM; ++m) {
        bool sw = cv > val[m];
        double tv = sw ? val[m] : cv; int ti = sw ? idx[m] : ci;
        val[m] = sw ? cv : val[m];    idx[m] = sw ? ci : idx[m];
        cv = tv; ci = ti;
      }
    }
  }
  double* vout = cval + ((((size_t)b * NC) + c) * nch + ch) * TOPM;
  int* iout = cidx + ((((size_t)b * NC) + c) * nch + ch) * TOPM;
#pragma unroll
  for (int m = 0; m < TOPM; ++m) { vout[m] = val[m]; iout[m] = idx[m]; }
}

__global__ __launch_bounds__(128) void merge_gather_old_kernel(
    const double* __restrict__ cval, const int* __restrict__ cidx,
    const float* __restrict__ y, float* __restrict__ out, int nch) {
  const int c = blockIdx.x;
  const int b = blockIdx.y;
  __shared__ float w_s[TOPM];
  __shared__ int i_s[TOPM];
  if (threadIdx.x == 0) {
    double val[TOPM]; int idx[TOPM];
#pragma unroll
    for (int m = 0; m < TOPM; ++m) { val[m] = -1e300; idx[m] = 0; }
    const double* vin = cval + (((size_t)b * NC) + c) * nch * TOPM;
    const int* iin = cidx + (((size_t)b * NC) + c) * nch * TOPM;
    for (int k = 0; k < nch; ++k) {
      const int base = k * TOPM;
      for (int m = 0; m < TOPM; ++m) {
        double s = vin[base + m];
        if (!(s > val[TOPM - 1])) break;
        double cv = s; int ci = iin[base + m];
#pragma unroll
        for (int mm = 0; mm < TOPM; ++mm) {
          bool sw = cv > val[mm];
          double tv = sw ? val[mm] : cv; int ti = sw ? idx[mm] : ci;
          val[mm] = sw ? cv : val[mm];   idx[mm] = sw ? ci : idx[mm];
          cv = tv; ci = ti;
        }
      }
    }
    double mx = val[0];
    double e[TOPM]; double sum = 0.0;
#pragma unroll
    for (int m = 0; m < TOPM; ++m) { e[m] = exp((val[m] - mx) * 10.0); sum += e[m]; }
    double inv = 1.0 / sum;
#pragma unroll
    for (int m = 0; m < TOPM; ++m) { w_s[m] = (float)(e[m] * inv); i_s[m] = idx[m]; }
  }
  __syncthreads();
  const int p = threadIdx.x;
  if (p < NP) {
    float acc = 0.f;
#pragma unroll
    for (int m = 0; m < TOPM; ++m)
      acc += w_s[m] * y[(((size_t)i_s[m]) * NP + p) * NC + c];
    out[(((size_t)b * NP) + p) * NC + c] = acc;
  }
}

extern "C" void kernel_launch(void* const* d_in, const int* in_sizes, int n_in,
                              void* d_out, int out_size, void* d_ws, size_t ws_size,
                              hipStream_t stream) {
  const float* x = (const float*)d_in[0];
  const float* ps = (const float*)d_in[1];
  const float* y = (const float*)d_in[2];
  float* out = (float*)d_out;
  char* ws = (char*)d_ws;

  const size_t qbytes = (size_t)NG * NB * NC * 4 * sizeof(double);        // 196,608
  const size_t phat32bytes = (size_t)NG * NT * NC * 4 * sizeof(float);    // 30.72 MB
  const size_t cvalbytes = (size_t)NB * NC * NCH * M1 * sizeof(float);    // 16.78 MB
  const size_t cidxbytes = (size_t)NB * NC * NCH * M1 * sizeof(int);      // 16.78 MB

  double* qbuf = (double*)ws;

  if (ws_size >= qbytes + phat32bytes + cvalbytes + cidxbytes) {
    float* phat = (float*)(ws + qbytes);
    float* cval = (float*)(ws + qbytes + phat32bytes);
    int* cidx = (int*)((char*)cval + cvalbytes);
    const int pn_blocks = (NT * NC + 511) / 512;  // 1250
    pre_kernel<<<dim3(NB + pn_blocks), dim3(512), 0, stream>>>(x, ps, qbuf, phat);
    sim32_kernel<<<dim3(NB / 16, NCH), dim3(1024), 0, stream>>>(phat, qbuf, cval, cidx);
    merge_gather_kernel<<<dim3(NC, NB), dim3(128), 0, stream>>>(cval, cidx, ps, qbuf,
                                                                y, out);
  } else {
    // fallback: round-1-proven all-fp64 path (pre_kernel qstat part only)
    pre_kernel<<<dim3(NB), dim3(512), 0, stream>>>(x, ps, qbuf, (float*)nullptr);
    const size_t per_ch = (size_t)NB * NC * TOPM * (sizeof(double) + sizeof(int));
    int nch = 1;
    if (ws_size > qbytes) {
      size_t mc = (ws_size - qbytes) / per_ch;
      nch = mc < 32 ? (int)mc : 32;
      if (nch < 1) nch = 1;
    }
    const int chunk = (NT + nch - 1) / nch;
    double* cval = (double*)(ws + qbytes);
    int* cidx = (int*)((char*)cval + (size_t)NB * NC * nch * TOPM * sizeof(double));
    sim_topk_inline_kernel<<<dim3(nch, NB / 4), dim3(256), 0, stream>>>(
        ps, qbuf, cval, cidx, nch, chunk);
    merge_gather_old_kernel<<<dim3(NC, NB), dim3(128), 0, stream>>>(cval, cidx, y, out, nch);
  }
}